// Round 3
// baseline (839.607 us; speedup 1.0000x reference)
//
#include <hip/hip_runtime.h>
#include <hip/hip_bf16.h>
#include <math.h>

#define N_NODES 50000
#define N_EDGES 500000
#define B_GRAPHS 8
#define NPG 6250
#define HID 64
#define HO 128          // HEADS*HID
#define IN_DIM 10
#define F_TOT 266       // IN_DIM + 4*HID
#define OUT_C 532       // 2*F_TOT
#define NEG_SLOPE 0.2f
#define NT_ROWS 44      // 7 etype + 31 rid + 2 rc + 3 rp + 1 const
#define SCB 200         // scan blocks
#define SCH 250         // scan chunk (SCB*SCH == N_NODES)

typedef short bf16x8 __attribute__((ext_vector_type(8)));
typedef float f32x4 __attribute__((ext_vector_type(4)));
typedef float f32x2 __attribute__((ext_vector_type(2)));
typedef unsigned u32x2v __attribute__((ext_vector_type(2)));

// dtype-agnostic float load: f32 flag chooses fp32 or bf16 interpretation
__device__ __forceinline__ float LD(const void* p, size_t i, int f32) {
    if (f32) return ((const float*)p)[i];
    unsigned u = ((const unsigned short*)p)[i];
    return __uint_as_float(u << 16);
}
__device__ __forceinline__ unsigned fkey(float f) {
    unsigned b = __float_as_uint(f);
    return (b & 0x80000000u) ? ~b : (b | 0x80000000u);
}
__device__ __forceinline__ float funkey(unsigned k) {
    unsigned b = (k & 0x80000000u) ? (k & 0x7fffffffu) : ~k;
    return __uint_as_float(b);
}
__device__ __forceinline__ unsigned short rnebf(float x) {
    unsigned u = __float_as_uint(x);
    return (unsigned short)((u + 0x7FFFu + ((u >> 16) & 1u)) >> 16);
}
__device__ __forceinline__ unsigned pk2(float lo, float hi) {
    return (unsigned)rnebf(lo) | ((unsigned)rnebf(hi) << 16);
}
__device__ __forceinline__ float plo(unsigned u) { return __uint_as_float(u << 16); }
__device__ __forceinline__ float phi(unsigned u) { return __uint_as_float(u & 0xFFFF0000u); }
// unpack a (lo,hi) bf16 pair to float2
__device__ __forceinline__ f32x2 up2(unsigned u) {
    return (f32x2){__uint_as_float(u << 16), __uint_as_float(u & 0xFFFF0000u)};
}
// half-wave swap via the backend-modeled intrinsic (NOT inline asm: two "+v"
// asm operands fed the same value can be register-coalesced into ONE VGPR,
// turning the swap into v_permlane32_swap v5,v5 — the round-2 correctness bug).
// r.x = [a_lo|b_lo], r.y = [a_hi|b_hi]
__device__ __forceinline__ void pswap(float& a, float& b) {
    u32x2v r = __builtin_amdgcn_permlane32_swap(__float_as_uint(a), __float_as_uint(b),
                                                false, false);
    a = __uint_as_float(r.x);
    b = __uint_as_float(r.y);
}

// ---------------- dtype detection ------------------------------------------
__global__ void k_detect(const void* __restrict__ att_rc, int* __restrict__ flagp) {
    __shared__ int cnt;
    if (threadIdx.x == 0) cnt = 0;
    __syncthreads();
    const unsigned short* w = (const unsigned short*)att_rc;
    int c = 0;
    for (int i = threadIdx.x; i < 8192; i += 256) {
        unsigned e = (w[i] >> 7) & 0xFF;
        if (e >= 0xC0) c++;
    }
    atomicAdd(&cnt, c);
    __syncthreads();
    if (threadIdx.x == 0) *flagp = (cnt > 8) ? 1 : 0;
}

// ---------------- weight pre-pack to bf16 (transposed LDS layouts) ----------
// pw_n[((l*3+m)*128+c)*64+k], pw_m0[(l*128+c)*128+k], pw_m1[(l*64+c)*128+k]
__global__ void k_wprep(const void* __restrict__ W_ni, const void* __restrict__ W_nj,
                        const void* __restrict__ W_node, const void* __restrict__ Wm0,
                        const void* __restrict__ Wm1,
                        unsigned short* __restrict__ pw_n,
                        unsigned short* __restrict__ pw_m0,
                        unsigned short* __restrict__ pw_m1,
                        const int* __restrict__ flagp) {
    const int f32 = *flagp;
    int i = blockIdx.x * 256 + threadIdx.x;
    if (i < 73728) {                      // 3l x 3m x 128c x 64k
        int k = i & 63, c = (i >> 6) & 127, lm = i >> 13;
        int m = lm % 3, l = lm / 3;
        const void* W = (m == 0) ? W_ni : (m == 1) ? W_nj : W_node;
        pw_n[i] = rnebf(LD(W, (size_t)l * 8192 + k * 128 + c, f32));
    } else if (i < 73728 + 49152) {       // 3l x 128c x 128k
        int j = i - 73728;
        int k = j & 127, c = (j >> 7) & 127, l = j >> 14;
        pw_m0[j] = rnebf(LD(Wm0, (size_t)l * 16384 + k * 128 + c, f32));
    } else if (i < 147456) {              // 3l x 64c x 128k
        int j = i - 122880;
        int k = j & 127, c = (j >> 7) & 63, l = j >> 13;
        pw_m1[j] = rnebf(LD(Wm1, (size_t)l * 8192 + k * 64 + c, f32));
    }
}

// ---------------- CSR build ------------------------------------------------
__global__ void k_count(const int* __restrict__ dst, int* __restrict__ cnt) {
    int i = blockIdx.x * blockDim.x + threadIdx.x;
    int stride = gridDim.x * blockDim.x;
    for (int e = i; e < N_EDGES; e += stride) atomicAdd(&cnt[dst[e]], 1);
}

__global__ void k_scan1(const int* __restrict__ cnt, int* __restrict__ bsum) {
    __shared__ int red[256];
    int b = blockIdx.x, t = threadIdx.x;
    red[t] = (t < SCH) ? cnt[b * SCH + t] : 0;
    __syncthreads();
    for (int off = 128; off; off >>= 1) {
        if (t < off) red[t] += red[t + off];
        __syncthreads();
    }
    if (t == 0) bsum[b] = red[0];
}
__global__ void k_scan2(const int* __restrict__ bsum, int* __restrict__ boff) {
    __shared__ int ts[256];
    int t = threadIdx.x;
    int v = (t < SCB) ? bsum[t] : 0;
    ts[t] = v;
    __syncthreads();
    for (int off = 1; off < 256; off <<= 1) {
        int u = (t >= off) ? ts[t - off] : 0;
        __syncthreads();
        ts[t] += u;
        __syncthreads();
    }
    if (t < SCB) boff[t] = ts[t] - v;
}
__global__ void k_scan3(const int* __restrict__ cnt, const int* __restrict__ boff,
                        int* __restrict__ rowptr, int* __restrict__ cursor) {
    __shared__ int ts[256];
    int b = blockIdx.x, t = threadIdx.x;
    int base = b * SCH;
    int v = (t < SCH) ? cnt[base + t] : 0;
    ts[t] = v;
    __syncthreads();
    for (int off = 1; off < 256; off <<= 1) {
        int u = (t >= off) ? ts[t - off] : 0;
        __syncthreads();
        ts[t] += u;
        __syncthreads();
    }
    if (t < SCH) {
        int r = boff[b] + ts[t] - v;
        rowptr[base + t] = r;
        cursor[base + t] = r;
    }
    if (b == SCB - 1 && t == SCH - 1) rowptr[N_NODES] = boff[b] + ts[t];
}

// emeta.w = etype | rid<<3 | src<<8   (src < 65536)
__global__ void k_fill(const int* __restrict__ src, const int* __restrict__ dst,
                       const int* __restrict__ etype, const int* __restrict__ rid,
                       const void* __restrict__ att_rc, const void* __restrict__ att_rp,
                       int* __restrict__ cursor, uint4* __restrict__ emeta,
                       const int* __restrict__ flagp) {
    const int f32 = *flagp;
    int i = blockIdx.x * blockDim.x + threadIdx.x;
    int stride = gridDim.x * blockDim.x;
    for (int e = i; e < N_EDGES; e += stride) {
        int d = dst[e];
        int j = atomicAdd(&cursor[d], 1);
        float rc0 = LD(att_rc, 2 * (size_t)e, f32), rc1 = LD(att_rc, 2 * (size_t)e + 1, f32);
        float rp0 = LD(att_rp, 3 * (size_t)e, f32), rp1 = LD(att_rp, 3 * (size_t)e + 1, f32),
              rp2 = LD(att_rp, 3 * (size_t)e + 2, f32);
        uint4 m;
        m.x = pk2(rc0, rc1);
        m.y = pk2(rp0, rp1);
        m.z = pk2(rp2, 0.f);
        m.w = (unsigned)(etype[e] | (rid[e] << 3) | ((unsigned)src[e] << 8));
        emeta[j] = m;
    }
}

// ---------------- initial feature MLP --------------------------------------
__global__ void k_init(const void* __restrict__ feat,
                       const void* __restrict__ W0, const void* __restrict__ b0,
                       const void* __restrict__ W1, const void* __restrict__ b1,
                       float* __restrict__ feats, const int* __restrict__ flagp) {
    const int f32 = *flagp;
    __shared__ float sf[64 * 12];
    __shared__ float sW0[IN_DIM * 64];
    __shared__ float sb0[64], sb1[64];
    __shared__ float sh[64 * 64];
    __shared__ float sW1[64 * 64];
    int tid = threadIdx.x, n0 = blockIdx.x * 64;
    for (int i = tid; i < IN_DIM * 64; i += 256) sW0[i] = LD(W0, i, f32);
    for (int i = tid; i < 64; i += 256) { sb0[i] = LD(b0, i, f32); sb1[i] = LD(b1, i, f32); }
    for (int i = tid; i < 64 * 64; i += 256) sW1[i] = LD(W1, i, f32);
    for (int i = tid; i < 64 * IN_DIM; i += 256) {
        int n = n0 + i / IN_DIM, c = i % IN_DIM;
        sf[(i / IN_DIM) * 12 + c] = (n < N_NODES) ? LD(feat, (size_t)n * IN_DIM + c, f32) : 0.f;
    }
    __syncthreads();
    int ng = tid / 16, cg = tid % 16;
    float acc[4][4];
    #pragma unroll
    for (int i = 0; i < 4; i++)
        #pragma unroll
        for (int j = 0; j < 4; j++) acc[i][j] = sb0[cg * 4 + j];
    #pragma unroll
    for (int k = 0; k < IN_DIM; k++)
        #pragma unroll
        for (int i = 0; i < 4; i++) {
            float a = sf[(ng * 4 + i) * 12 + k];
            #pragma unroll
            for (int j = 0; j < 4; j++) acc[i][j] += a * sW0[k * 64 + cg * 4 + j];
        }
    #pragma unroll
    for (int i = 0; i < 4; i++)
        #pragma unroll
        for (int j = 0; j < 4; j++) sh[(ng * 4 + i) * 64 + cg * 4 + j] = fmaxf(acc[i][j], 0.f);
    __syncthreads();
    float o[4][4];
    #pragma unroll
    for (int i = 0; i < 4; i++)
        #pragma unroll
        for (int j = 0; j < 4; j++) o[i][j] = sb1[cg * 4 + j];
    for (int k = 0; k < 64; k++) {
        float4 bv = *(const float4*)&sW1[k * 64 + cg * 4];
        #pragma unroll
        for (int i = 0; i < 4; i++) {
            float a = sh[(ng * 4 + i) * 64 + k];
            o[i][0] += a * bv.x; o[i][1] += a * bv.y;
            o[i][2] += a * bv.z; o[i][3] += a * bv.w;
        }
    }
    #pragma unroll
    for (int i = 0; i < 4; i++) {
        int n = n0 + ng * 4 + i;
        if (n < N_NODES) {
            float* r = feats + (size_t)n * F_TOT;
            #pragma unroll
            for (int j = 0; j < 4; j++) r[IN_DIM + cg * 4 + j] = o[i][j];
        }
    }
    for (int i = tid; i < 64 * IN_DIM; i += 256) {
        int n = n0 + i / IN_DIM, c = i % IN_DIM;
        if (n < N_NODES) feats[(size_t)n * F_TOT + c] = sf[(i / IN_DIM) * 12 + c];
    }
}

// ---------------- fused edge tables ----------------------------------------
__global__ void k_tables(const void* __restrict__ etype_emb, const void* __restrict__ rid_emb,
                         const void* __restrict__ rc_W, const void* __restrict__ rc_b,
                         const void* __restrict__ rp_W, const void* __restrict__ rp_b,
                         const void* __restrict__ W_fij, const void* __restrict__ egat_bias,
                         float* __restrict__ T, const int* __restrict__ flagp) {
    const int f32 = *flagp;
    int l = blockIdx.x;
    __shared__ float S[NT_ROWS * HID];
    __shared__ float W[HID * HO];
    for (int i = threadIdx.x; i < 7 * HID; i += 256) S[i] = LD(etype_emb, i, f32);
    for (int i = threadIdx.x; i < 31 * HID; i += 256) S[7 * HID + i] = LD(rid_emb, i, f32);
    for (int i = threadIdx.x; i < 2 * HID; i += 256) S[38 * HID + i] = LD(rc_W, i, f32);
    for (int i = threadIdx.x; i < 3 * HID; i += 256) S[40 * HID + i] = LD(rp_W, i, f32);
    for (int i = threadIdx.x; i < HID; i += 256)
        S[43 * HID + i] = LD(rc_b, i, f32) + LD(rp_b, i, f32);
    for (int i = threadIdx.x; i < HID * HO; i += 256)
        W[i] = LD(W_fij, (size_t)l * HID * HO + i, f32);
    __syncthreads();
    for (int idx = threadIdx.x; idx < NT_ROWS * HO; idx += 256) {
        int r = idx / HO, c = idx % HO;
        float acc = (r == 43) ? LD(egat_bias, l * HO + c, f32) : 0.f;
        for (int k = 0; k < HID; k++) acc += S[r * HID + k] * W[k * HO + c];
        T[(size_t)l * NT_ROWS * HO + idx] = acc;
    }
}

// ---------------- node GEMMs via MFMA -> packed bf16 gather buffers --------
__global__ void __launch_bounds__(256) k_ngemm(
        const float* __restrict__ feats, int h_off,
        const unsigned short* __restrict__ pw_n, int l,
        unsigned* __restrict__ gsrc, unsigned* __restrict__ gdst) {
    __shared__ __align__(16) unsigned short Xs[64 * 72];
    __shared__ __align__(16) unsigned short Ws[384 * 72];
    int tid = threadIdx.x, n0 = blockIdx.x * 64;
    for (int i = tid; i < 64 * 64; i += 256) {
        int n = i >> 6, c = i & 63, gn = n0 + n;
        Xs[n * 72 + c] = rnebf((gn < N_NODES) ? feats[(size_t)gn * F_TOT + h_off + c] : 0.f);
    }
    const uint4* pn = (const uint4*)pw_n + (size_t)l * 3072;
    for (int i = tid; i < 3072; i += 256) {   // i = (m*128+c)*8 + kq
        int kq = i & 7, mc = i >> 3;
        *(uint4*)&Ws[mc * 72 + kq * 8] = pn[i];
    }
    __syncthreads();
    int wid = tid >> 6, lane = tid & 63;
    int row0 = wid * 16, mrow = lane & 15, quad = lane >> 4;
    bf16x8 a0 = *(const bf16x8*)&Xs[(row0 + mrow) * 72 + quad * 8];
    bf16x8 a1 = *(const bf16x8*)&Xs[(row0 + mrow) * 72 + 32 + quad * 8];
    f32x4 accA[8], accB[8];
    #pragma unroll
    for (int j = 0; j < 8; j++) { accA[j] = (f32x4){0,0,0,0}; accB[j] = (f32x4){0,0,0,0}; }
    #pragma unroll
    for (int j = 0; j < 8; j++) {
        bf16x8 b0 = *(const bf16x8*)&Ws[(0 * 128 + j * 16 + mrow) * 72 + quad * 8];
        bf16x8 b1 = *(const bf16x8*)&Ws[(0 * 128 + j * 16 + mrow) * 72 + 32 + quad * 8];
        accA[j] = __builtin_amdgcn_mfma_f32_16x16x32_bf16(a0, b0, accA[j], 0, 0, 0);
        accA[j] = __builtin_amdgcn_mfma_f32_16x16x32_bf16(a1, b1, accA[j], 0, 0, 0);
        bf16x8 c0 = *(const bf16x8*)&Ws[(2 * 128 + j * 16 + mrow) * 72 + quad * 8];
        bf16x8 c1 = *(const bf16x8*)&Ws[(2 * 128 + j * 16 + mrow) * 72 + 32 + quad * 8];
        accB[j] = __builtin_amdgcn_mfma_f32_16x16x32_bf16(a0, c0, accB[j], 0, 0, 0);
        accB[j] = __builtin_amdgcn_mfma_f32_16x16x32_bf16(a1, c1, accB[j], 0, 0, 0);
    }
    #pragma unroll
    for (int j = 0; j < 4; j++) {
        int c = j * 16 + mrow;
        #pragma unroll
        for (int r = 0; r < 4; r++) {
            int gn = n0 + row0 + quad * 4 + r;
            if (gn < N_NODES) {
                uint2 v;
                v.x = pk2(accA[j][r], accA[j + 4][r]);
                v.y = pk2(accB[j][r], accB[j + 4][r]);
                *(uint2*)&gsrc[(size_t)gn * 128 + c * 2] = v;
            }
        }
    }
    f32x4 accC[8];
    #pragma unroll
    for (int j = 0; j < 8; j++) accC[j] = (f32x4){0,0,0,0};
    #pragma unroll
    for (int j = 0; j < 8; j++) {
        bf16x8 b0 = *(const bf16x8*)&Ws[(1 * 128 + j * 16 + mrow) * 72 + quad * 8];
        bf16x8 b1 = *(const bf16x8*)&Ws[(1 * 128 + j * 16 + mrow) * 72 + 32 + quad * 8];
        accC[j] = __builtin_amdgcn_mfma_f32_16x16x32_bf16(a0, b0, accC[j], 0, 0, 0);
        accC[j] = __builtin_amdgcn_mfma_f32_16x16x32_bf16(a1, b1, accC[j], 0, 0, 0);
    }
    #pragma unroll
    for (int j = 0; j < 4; j++) {
        int c = j * 16 + mrow;
        #pragma unroll
        for (int r = 0; r < 4; r++) {
            int gn = n0 + row0 + quad * 4 + r;
            if (gn < N_NODES)
                gdst[(size_t)gn * 64 + c] = pk2(accC[j][r], accC[j + 4][r]);
        }
    }
}

// ---------------- fused edge phase -----------------------------------------
// Round-9: round-8's 4-deep pipeline + single-exp split-space softmax, with
// the permlane32_swap done via __builtin_amdgcn_permlane32_swap (fixes the
// same-register coalescing bug that broke round-8's numerics).
__global__ void __launch_bounds__(256) k_edge_fused(
        const float* __restrict__ T, const void* __restrict__ attn, int l,
        const unsigned* __restrict__ gsrc, const unsigned* __restrict__ gdst,
        const int* __restrict__ rowptr, const uint4* __restrict__ emeta,
        float* __restrict__ h_att, const int* __restrict__ flagp) {
    const int f32 = *flagp;
    __shared__ f32x2 Ts2[38 * 64];          // [row][lane] = {head0, head1}
    const float* Tl = T + (size_t)l * NT_ROWS * HO;
    int tid = threadIdx.x;
    for (int i = tid; i < 38 * 64; i += 256) {
        int r = i >> 6, c = i & 63;
        Ts2[i] = (f32x2){Tl[r * HO + c], Tl[r * HO + 64 + c]};
    }
    int lane = tid & 63;
    f32x2 C2[6];
    #pragma unroll
    for (int r = 0; r < 6; r++)
        C2[r] = (f32x2){Tl[(38 + r) * HO + lane], Tl[(38 + r) * HO + 64 + lane]};
    f32x2 AT2 = (f32x2){LD(attn, l * HO + lane, f32), LD(attn, l * HO + 64 + lane, f32)};
    __syncthreads();
    int wid = tid >> 6;
    int d0 = blockIdx.x * 8 + wid * 2;

    #pragma unroll 1
    for (int dn = 0; dn < 2; dn++) {
        int d = d0 + dn;
        int jb = rowptr[d], je = rowptr[d + 1];
        unsigned gd = gdst[(size_t)d * 64 + lane];
        f32x2 NJ2 = up2(gd) + C2[5];         // const row folded in
        f32x2 A2 = (f32x2){0.f, 0.f};
        float Lsp = 0.f;                     // split-space denominator

        // -> s_out: head0 sum in lanes 0-31, head1 sum in lanes 32-63 (pre-exp)
        auto logits = [&](const uint4& em, const uint2& g, float& s_out, f32x2& h2) {
            unsigned w = em.w;
            int et = (int)(w & 7u), ri = (int)((w >> 3) & 31u);
            f32x2 x = up2(g.x) + NJ2;
            x += Ts2[et * 64 + lane];
            x += Ts2[(7 + ri) * 64 + lane];
            x += plo(em.x) * C2[0];
            x += phi(em.x) * C2[1];
            x += plo(em.y) * C2[2];
            x += phi(em.y) * C2[3];
            x += plo(em.z) * C2[4];
            f32x2 xs = x * NEG_SLOPE;        // leaky = max(x, 0.2x) for slope<1
            x.x = fmaxf(x.x, xs.x);
            x.y = fmaxf(x.y, xs.y);
            f32x2 p = x * AT2;
            h2 = up2(g.y);
            float pa = p.x, pb = p.y;
            pswap(pa, pb);                   // pa=[p0_lo|p1_lo], pb=[p0_hi|p1_hi]
            float s = pa + pb;               // lanes 0-31: head0, 32-63: head1
            s += __int_as_float(__builtin_amdgcn_update_dpp(0, __float_as_int(s), 0xB1, 0xF, 0xF, true));
            s += __int_as_float(__builtin_amdgcn_update_dpp(0, __float_as_int(s), 0x4E, 0xF, 0xF, true));
            s += __int_as_float(__builtin_amdgcn_update_dpp(0, __float_as_int(s), 0x141, 0xF, 0xF, true));
            s += __int_as_float(__builtin_amdgcn_update_dpp(0, __float_as_int(s), 0x140, 0xF, 0xF, true));
            s += __int_as_float(__builtin_amdgcn_ds_swizzle(__float_as_int(s), 0x401F));
            s_out = s;
        };
        auto update = [&](float s, f32x2 h2) {
            float w = __expf(s);             // one exp covers both heads
            Lsp += w;
            float wa = w, wb = w;
            pswap(wa, wb);                   // wa = w0 all lanes, wb = w1 all lanes
            A2 += (f32x2){wa, wb} * h2;
        };
        auto fetch = [&](int j, uint4& em, uint2& g) {
            em = emeta[j];
            g = *(const uint2*)&gsrc[(size_t)(em.w >> 8) * 128 + lane * 2];
        };

        uint4 emA = make_uint4(0,0,0,0), emB = make_uint4(0,0,0,0);
        uint4 emC = make_uint4(0,0,0,0), emD = make_uint4(0,0,0,0);
        uint2 gA = make_uint2(0,0), gB = make_uint2(0,0);
        uint2 gC = make_uint2(0,0), gD = make_uint2(0,0);
        int j = jb;
        if (j < je)     fetch(j,     emA, gA);
        if (j + 1 < je) fetch(j + 1, emB, gB);
        if (j + 2 < je) fetch(j + 2, emC, gC);
        if (j + 3 < je) fetch(j + 3, emD, gD);
        while (j + 4 <= je) {
            float sA, sB, sC, sD;
            f32x2 hA, hB, hC, hD;
            logits(emA, gA, sA, hA);         // 4 independent chains
            logits(emB, gB, sB, hB);
            logits(emC, gC, sC, hC);
            logits(emD, gD, sD, hD);
            if (j + 4 < je) fetch(j + 4, emA, gA);
            if (j + 5 < je) fetch(j + 5, emB, gB);
            if (j + 6 < je) fetch(j + 6, emC, gC);
            if (j + 7 < je) fetch(j + 7, emD, gD);
            update(sA, hA);
            update(sB, hB);
            update(sC, hC);
            update(sD, hD);
            j += 4;
        }
        int rem = je - j;
        if (rem > 0) { float s; f32x2 h; logits(emA, gA, s, h); update(s, h); }
        if (rem > 1) { float s; f32x2 h; logits(emB, gB, s, h); update(s, h); }
        if (rem > 2) { float s; f32x2 h; logits(emC, gC, s, h); update(s, h); }

        float la = Lsp, lb = Lsp;
        pswap(la, lb);                       // la = L0 all lanes, lb = L1 all lanes
        h_att[(size_t)d * HO + lane]      = A2.x / (la + 1e-9f);
        h_att[(size_t)d * HO + 64 + lane] = A2.y / (lb + 1e-9f);
    }
}

// ---------------- node MLP + residual via MFMA ------------------------------
__global__ void __launch_bounds__(256) k_mlp(
        const float* __restrict__ h_att,
        const unsigned short* __restrict__ pw_m0, const void* __restrict__ bm0,
        const unsigned short* __restrict__ pw_m1, const void* __restrict__ bm1, int l,
        float* __restrict__ feats, int prev_off, int out_off,
        const int* __restrict__ flagp) {
    const int f32 = *flagp;
    __shared__ __align__(16) unsigned short Xs[64 * 136];
    __shared__ __align__(16) unsigned short W0T[128 * 136];
    __shared__ __align__(16) unsigned short W1T[64 * 136];
    __shared__ float sb0[HO], sb1[64];
    int tid = threadIdx.x, n0 = blockIdx.x * 64;
    for (int i = tid; i < 64 * 128; i += 256) {
        int n = i >> 7, c = i & 127, gn = n0 + n;
        Xs[n * 136 + c] = rnebf((gn < N_NODES) ? h_att[(size_t)gn * HO + c] : 0.f);
    }
    const uint4* p0 = (const uint4*)pw_m0 + (size_t)l * 2048;
    for (int i = tid; i < 2048; i += 256) {   // i = c*16 + kq
        int kq = i & 15, c = i >> 4;
        *(uint4*)&W0T[c * 136 + kq * 8] = p0[i];
    }
    const uint4* p1 = (const uint4*)pw_m1 + (size_t)l * 1024;
    for (int i = tid; i < 1024; i += 256) {
        int kq = i & 15, c = i >> 4;
        *(uint4*)&W1T[c * 136 + kq * 8] = p1[i];
    }
    for (int i = tid; i < HO; i += 256) sb0[i] = LD(bm0, l * HO + i, f32);
    for (int i = tid; i < 64; i += 256) sb1[i] = LD(bm1, l * 64 + i, f32);
    __syncthreads();
    int wid = tid >> 6, lane = tid & 63;
    int row0 = wid * 16, mrow = lane & 15, quad = lane >> 4;
    f32x4 acc[8];
    #pragma unroll
    for (int j = 0; j < 8; j++) {
        float b = sb0[j * 16 + mrow];
        acc[j] = (f32x4){b, b, b, b};
    }
    #pragma unroll
    for (int ks = 0; ks < 4; ks++) {
        bf16x8 a = *(const bf16x8*)&Xs[(row0 + mrow) * 136 + ks * 32 + quad * 8];
        #pragma unroll
        for (int j = 0; j < 8; j++) {
            bf16x8 b = *(const bf16x8*)&W0T[(j * 16 + mrow) * 136 + ks * 32 + quad * 8];
            acc[j] = __builtin_amdgcn_mfma_f32_16x16x32_bf16(a, b, acc[j], 0, 0, 0);
        }
    }
    #pragma unroll
    for (int j = 0; j < 8; j++)
        #pragma unroll
        for (int r = 0; r < 4; r++)
            Xs[(row0 + quad * 4 + r) * 136 + j * 16 + mrow] = rnebf(fmaxf(acc[j][r], 0.f));
    f32x4 o[4];
    #pragma unroll
    for (int j = 0; j < 4; j++) {
        float b = sb1[j * 16 + mrow];
        o[j] = (f32x4){b, b, b, b};
    }
    #pragma unroll
    for (int ks = 0; ks < 4; ks++) {
        bf16x8 a = *(const bf16x8*)&Xs[(row0 + mrow) * 136 + ks * 32 + quad * 8];
        #pragma unroll
        for (int j = 0; j < 4; j++) {
            bf16x8 b = *(const bf16x8*)&W1T[(j * 16 + mrow) * 136 + ks * 32 + quad * 8];
            o[j] = __builtin_amdgcn_mfma_f32_16x16x32_bf16(a, b, o[j], 0, 0, 0);
        }
    }
    #pragma unroll
    for (int j = 0; j < 4; j++) {
        int c = j * 16 + mrow;
        #pragma unroll
        for (int r = 0; r < 4; r++) {
            int gn = n0 + row0 + quad * 4 + r;
            if (gn < N_NODES) {
                float* rw = feats + (size_t)gn * F_TOT;
                rw[out_off + c] = o[j][r] + rw[prev_off + c];
            }
        }
    }
}

// ---------------- graph max pool -------------------------------------------
__global__ void k_pool(const float* __restrict__ feats, unsigned* __restrict__ gmax) {
    int g = blockIdx.x;
    int chunk = blockIdx.y;
    int t = threadIdx.x;
    const int CS = 49;
    int nb = chunk * CS;
    int ne = (nb + CS < NPG) ? nb + CS : NPG;
    float m0 = -INFINITY, m1 = -INFINITY;
    for (int n = nb; n < ne; n++) {
        const float* row = feats + (size_t)(g * NPG + n) * F_TOT;
        m0 = fmaxf(m0, row[t]);
        if (t + 256 < F_TOT) m1 = fmaxf(m1, row[t + 256]);
    }
    atomicMax(&gmax[g * F_TOT + t], fkey(m0));
    if (t + 256 < F_TOT) atomicMax(&gmax[g * F_TOT + t + 256], fkey(m1));
}

// ---------------- output write: wave per row --------------------------------
__global__ void k_out(const float* __restrict__ feats, const unsigned* __restrict__ gmax,
                      void* __restrict__ out, const int* __restrict__ flagp) {
    const int f32 = *flagp;
    int lane = threadIdx.x & 63;
    int wave = (blockIdx.x * blockDim.x + threadIdx.x) >> 6;
    int nw = (gridDim.x * blockDim.x) >> 6;
    for (int row = wave; row < B_GRAPHS * NPG; row += nw) {
        int g = row / NPG;
        const float* fr = feats + (size_t)row * F_TOT;
        const unsigned* gr = gmax + g * F_TOT;
        if (f32) {
            float* o = (float*)out + (size_t)row * OUT_C;
            for (int c = lane; c < OUT_C; c += 64)
                o[c] = (c < F_TOT) ? fr[c] : funkey(gr[c - F_TOT]);
        } else {
            __hip_bfloat16* o = (__hip_bfloat16*)out + (size_t)row * OUT_C;
            for (int c = lane; c < OUT_C; c += 64)
                o[c] = __float2bfloat16((c < F_TOT) ? fr[c] : funkey(gr[c - F_TOT]));
        }
    }
}

extern "C" void kernel_launch(void* const* d_in, const int* in_sizes, int n_in,
                              void* d_out, int out_size, void* d_ws, size_t ws_size,
                              hipStream_t stream) {
    const void* feat      = d_in[0];
    const void* att_rc    = d_in[1];
    const void* att_rp    = d_in[2];
    const void* etype_emb = d_in[3];
    const void* rid_emb   = d_in[4];
    const void* rc_W      = d_in[5];
    const void* rc_b      = d_in[6];
    const void* rp_W      = d_in[7];
    const void* rp_b      = d_in[8];
    const void* fe_W0     = d_in[9];
    const void* fe_b0     = d_in[10];
    const void* fe_W1     = d_in[11];
    const void* fe_b1     = d_in[12];
    const void* W_ni      = d_in[13];
    const void* W_nj      = d_in[14];
    const void* W_fij     = d_in[15];
    const void* W_node    = d_in[16];
    const void* attn      = d_in[17];
    const void* egat_bias = d_in[18];
    const void* Wm0       = d_in[19];
    const void* bm0       = d_in[20];
    const void* Wm1       = d_in[21];
    const void* bm1       = d_in[22];
    const int* src   = (const int*)d_in[23];
    const int* dst   = (const int*)d_in[24];
    const int* etype = (const int*)d_in[25];
    const int* rid   = (const int*)d_in[26];

    char* p = (char*)d_ws;
    auto alloc = [&](size_t bytes) {
        char* r = p;
        p += (bytes + 255) & ~(size_t)255;
        return r;
    };
    float*    feats  = (float*)alloc((size_t)N_NODES * F_TOT * 4);
    unsigned* gsrc   = (unsigned*)alloc((size_t)N_NODES * HO * 4);
    unsigned* gdst   = (unsigned*)alloc((size_t)N_NODES * 64 * 4);
    float*    h_att  = (float*)alloc((size_t)N_NODES * HO * 4);
    float*    T      = (float*)alloc((size_t)3 * NT_ROWS * HO * 4);
    unsigned* gmax   = (unsigned*)alloc((size_t)B_GRAPHS * F_TOT * 4);
    int*      flagp  = (int*)alloc(256);
    int*      rowptr = (int*)alloc((size_t)(N_NODES + 1) * 4);
    int*      cursor = (int*)alloc((size_t)N_NODES * 4);
    int*      cnt    = (int*)alloc((size_t)N_NODES * 4);
    int*      bsum   = (int*)alloc((size_t)SCB * 4);
    int*      boff   = (int*)alloc((size_t)SCB * 4);
    uint4*    emeta  = (uint4*)alloc((size_t)N_EDGES * 16);
    unsigned short* pw_n  = (unsigned short*)alloc((size_t)73728 * 2);
    unsigned short* pw_m0 = (unsigned short*)alloc((size_t)49152 * 2);
    unsigned short* pw_m1 = (unsigned short*)alloc((size_t)24576 * 2);

    k_detect<<<1, 256, 0, stream>>>(att_rc, flagp);
    hipMemsetAsync(cnt, 0, (size_t)N_NODES * 4, stream);
    hipMemsetAsync(gmax, 0, (size_t)B_GRAPHS * F_TOT * 4, stream);
    k_wprep<<<576, 256, 0, stream>>>(W_ni, W_nj, W_node, Wm0, Wm1,
                                     pw_n, pw_m0, pw_m1, flagp);
    k_count<<<512, 256, 0, stream>>>(dst, cnt);
    k_scan1<<<SCB, 256, 0, stream>>>(cnt, bsum);
    k_scan2<<<1, 256, 0, stream>>>(bsum, boff);
    k_scan3<<<SCB, 256, 0, stream>>>(cnt, boff, rowptr, cursor);
    k_fill<<<1024, 256, 0, stream>>>(src, dst, etype, rid, att_rc, att_rp,
                                     cursor, emeta, flagp);
    k_init<<<(N_NODES + 63) / 64, 256, 0, stream>>>(feat, fe_W0, fe_b0, fe_W1, fe_b1,
                                                    feats, flagp);
    k_tables<<<3, 256, 0, stream>>>(etype_emb, rid_emb, rc_W, rc_b, rp_W, rp_b,
                                    W_fij, egat_bias, T, flagp);
    for (int l = 0; l < 3; l++) {
        int h_off = IN_DIM + l * HID;
        int out_off = IN_DIM + (l + 1) * HID;
        k_ngemm<<<(N_NODES + 63) / 64, 256, 0, stream>>>(feats, h_off, pw_n, l, gsrc, gdst);
        k_edge_fused<<<N_NODES / 8, 256, 0, stream>>>(T, attn, l, gsrc, gdst,
                                                      rowptr, emeta, h_att, flagp);
        k_mlp<<<(N_NODES + 63) / 64, 256, 0, stream>>>(h_att, pw_m0, bm0, pw_m1, bm1, l,
                                                       feats, h_off, out_off, flagp);
    }
    k_pool<<<dim3(B_GRAPHS, 128), 256, 0, stream>>>(feats, gmax);
    k_out<<<2048, 256, 0, stream>>>(feats, gmax, d_out, flagp);
}

// Round 4
// 755.370 us; speedup vs baseline: 1.1115x; 1.1115x over previous
//
#include <hip/hip_runtime.h>
#include <hip/hip_bf16.h>
#include <math.h>

#define N_NODES 50000
#define N_EDGES 500000
#define B_GRAPHS 8
#define NPG 6250
#define HID 64
#define HO 128          // HEADS*HID
#define IN_DIM 10
#define F_TOT 266       // IN_DIM + 4*HID
#define OUT_C 532       // 2*F_TOT
#define NEG_SLOPE 0.2f
#define NT_ROWS 44      // 7 etype + 31 rid + 2 rc + 3 rp + 1 const
#define SCB 200         // scan blocks
#define SCH 250         // scan chunk (SCB*SCH == N_NODES)

typedef short bf16x8 __attribute__((ext_vector_type(8)));
typedef float f32x4 __attribute__((ext_vector_type(4)));
typedef float f32x2 __attribute__((ext_vector_type(2)));
typedef unsigned u32x2v __attribute__((ext_vector_type(2)));

// dtype-agnostic float load: f32 flag chooses fp32 or bf16 interpretation
__device__ __forceinline__ float LD(const void* p, size_t i, int f32) {
    if (f32) return ((const float*)p)[i];
    unsigned u = ((const unsigned short*)p)[i];
    return __uint_as_float(u << 16);
}
__device__ __forceinline__ unsigned fkey(float f) {
    unsigned b = __float_as_uint(f);
    return (b & 0x80000000u) ? ~b : (b | 0x80000000u);
}
__device__ __forceinline__ float funkey(unsigned k) {
    unsigned b = (k & 0x80000000u) ? (k & 0x7fffffffu) : ~k;
    return __uint_as_float(b);
}
__device__ __forceinline__ unsigned short rnebf(float x) {
    unsigned u = __float_as_uint(x);
    return (unsigned short)((u + 0x7FFFu + ((u >> 16) & 1u)) >> 16);
}
__device__ __forceinline__ unsigned pk2(float lo, float hi) {
    return (unsigned)rnebf(lo) | ((unsigned)rnebf(hi) << 16);
}
__device__ __forceinline__ float plo(unsigned u) { return __uint_as_float(u << 16); }
__device__ __forceinline__ float phi(unsigned u) { return __uint_as_float(u & 0xFFFF0000u); }
// unpack a (lo,hi) bf16 pair to float2
__device__ __forceinline__ f32x2 up2(unsigned u) {
    return (f32x2){__uint_as_float(u << 16), __uint_as_float(u & 0xFFFF0000u)};
}
// half-wave swap via the backend-modeled intrinsic (NOT inline asm: two "+v"
// asm operands fed the same value can be register-coalesced into ONE VGPR,
// turning the swap into v_permlane32_swap v5,v5 — the round-2 correctness bug).
// r.x = [a_lo|b_lo], r.y = [a_hi|b_hi]
__device__ __forceinline__ void pswap(float& a, float& b) {
    u32x2v r = __builtin_amdgcn_permlane32_swap(__float_as_uint(a), __float_as_uint(b),
                                                false, false);
    a = __uint_as_float(r.x);
    b = __uint_as_float(r.y);
}

// ---------------- dtype detection ------------------------------------------
__global__ void k_detect(const void* __restrict__ att_rc, int* __restrict__ flagp) {
    __shared__ int cnt;
    if (threadIdx.x == 0) cnt = 0;
    __syncthreads();
    const unsigned short* w = (const unsigned short*)att_rc;
    int c = 0;
    for (int i = threadIdx.x; i < 8192; i += 256) {
        unsigned e = (w[i] >> 7) & 0xFF;
        if (e >= 0xC0) c++;
    }
    atomicAdd(&cnt, c);
    __syncthreads();
    if (threadIdx.x == 0) *flagp = (cnt > 8) ? 1 : 0;
}

// ---------------- weight pre-pack to bf16 (transposed LDS layouts) ----------
// pw_n[((l*3+m)*128+c)*64+k], pw_m0[(l*128+c)*128+k], pw_m1[(l*64+c)*128+k]
__global__ void k_wprep(const void* __restrict__ W_ni, const void* __restrict__ W_nj,
                        const void* __restrict__ W_node, const void* __restrict__ Wm0,
                        const void* __restrict__ Wm1,
                        unsigned short* __restrict__ pw_n,
                        unsigned short* __restrict__ pw_m0,
                        unsigned short* __restrict__ pw_m1,
                        const int* __restrict__ flagp) {
    const int f32 = *flagp;
    int i = blockIdx.x * 256 + threadIdx.x;
    if (i < 73728) {                      // 3l x 3m x 128c x 64k
        int k = i & 63, c = (i >> 6) & 127, lm = i >> 13;
        int m = lm % 3, l = lm / 3;
        const void* W = (m == 0) ? W_ni : (m == 1) ? W_nj : W_node;
        pw_n[i] = rnebf(LD(W, (size_t)l * 8192 + k * 128 + c, f32));
    } else if (i < 73728 + 49152) {       // 3l x 128c x 128k
        int j = i - 73728;
        int k = j & 127, c = (j >> 7) & 127, l = j >> 14;
        pw_m0[j] = rnebf(LD(Wm0, (size_t)l * 16384 + k * 128 + c, f32));
    } else if (i < 147456) {              // 3l x 64c x 128k
        int j = i - 122880;
        int k = j & 127, c = (j >> 7) & 63, l = j >> 13;
        pw_m1[j] = rnebf(LD(Wm1, (size_t)l * 8192 + k * 64 + c, f32));
    }
}

// ---------------- CSR build ------------------------------------------------
__global__ void k_count(const int* __restrict__ dst, int* __restrict__ cnt) {
    int i = blockIdx.x * blockDim.x + threadIdx.x;
    int stride = gridDim.x * blockDim.x;
    for (int e = i; e < N_EDGES; e += stride) atomicAdd(&cnt[dst[e]], 1);
}

__global__ void k_scan1(const int* __restrict__ cnt, int* __restrict__ bsum) {
    __shared__ int red[256];
    int b = blockIdx.x, t = threadIdx.x;
    red[t] = (t < SCH) ? cnt[b * SCH + t] : 0;
    __syncthreads();
    for (int off = 128; off; off >>= 1) {
        if (t < off) red[t] += red[t + off];
        __syncthreads();
    }
    if (t == 0) bsum[b] = red[0];
}
__global__ void k_scan2(const int* __restrict__ bsum, int* __restrict__ boff) {
    __shared__ int ts[256];
    int t = threadIdx.x;
    int v = (t < SCB) ? bsum[t] : 0;
    ts[t] = v;
    __syncthreads();
    for (int off = 1; off < 256; off <<= 1) {
        int u = (t >= off) ? ts[t - off] : 0;
        __syncthreads();
        ts[t] += u;
        __syncthreads();
    }
    if (t < SCB) boff[t] = ts[t] - v;
}
__global__ void k_scan3(const int* __restrict__ cnt, const int* __restrict__ boff,
                        int* __restrict__ rowptr, int* __restrict__ cursor) {
    __shared__ int ts[256];
    int b = blockIdx.x, t = threadIdx.x;
    int base = b * SCH;
    int v = (t < SCH) ? cnt[base + t] : 0;
    ts[t] = v;
    __syncthreads();
    for (int off = 1; off < 256; off <<= 1) {
        int u = (t >= off) ? ts[t - off] : 0;
        __syncthreads();
        ts[t] += u;
        __syncthreads();
    }
    if (t < SCH) {
        int r = boff[b] + ts[t] - v;
        rowptr[base + t] = r;
        cursor[base + t] = r;
    }
    if (b == SCB - 1 && t == SCH - 1) rowptr[N_NODES] = boff[b] + ts[t];
}

// emeta.w = etype | rid<<3 | src<<8   (src < 65536)
__global__ void k_fill(const int* __restrict__ src, const int* __restrict__ dst,
                       const int* __restrict__ etype, const int* __restrict__ rid,
                       const void* __restrict__ att_rc, const void* __restrict__ att_rp,
                       int* __restrict__ cursor, uint4* __restrict__ emeta,
                       const int* __restrict__ flagp) {
    const int f32 = *flagp;
    int i = blockIdx.x * blockDim.x + threadIdx.x;
    int stride = gridDim.x * blockDim.x;
    for (int e = i; e < N_EDGES; e += stride) {
        int d = dst[e];
        int j = atomicAdd(&cursor[d], 1);
        float rc0 = LD(att_rc, 2 * (size_t)e, f32), rc1 = LD(att_rc, 2 * (size_t)e + 1, f32);
        float rp0 = LD(att_rp, 3 * (size_t)e, f32), rp1 = LD(att_rp, 3 * (size_t)e + 1, f32),
              rp2 = LD(att_rp, 3 * (size_t)e + 2, f32);
        uint4 m;
        m.x = pk2(rc0, rc1);
        m.y = pk2(rp0, rp1);
        m.z = pk2(rp2, 0.f);
        m.w = (unsigned)(etype[e] | (rid[e] << 3) | ((unsigned)src[e] << 8));
        emeta[j] = m;
    }
}

// ---------------- initial feature MLP --------------------------------------
__global__ void k_init(const void* __restrict__ feat,
                       const void* __restrict__ W0, const void* __restrict__ b0,
                       const void* __restrict__ W1, const void* __restrict__ b1,
                       float* __restrict__ feats, const int* __restrict__ flagp) {
    const int f32 = *flagp;
    __shared__ float sf[64 * 12];
    __shared__ float sW0[IN_DIM * 64];
    __shared__ float sb0[64], sb1[64];
    __shared__ float sh[64 * 64];
    __shared__ float sW1[64 * 64];
    int tid = threadIdx.x, n0 = blockIdx.x * 64;
    for (int i = tid; i < IN_DIM * 64; i += 256) sW0[i] = LD(W0, i, f32);
    for (int i = tid; i < 64; i += 256) { sb0[i] = LD(b0, i, f32); sb1[i] = LD(b1, i, f32); }
    for (int i = tid; i < 64 * 64; i += 256) sW1[i] = LD(W1, i, f32);
    for (int i = tid; i < 64 * IN_DIM; i += 256) {
        int n = n0 + i / IN_DIM, c = i % IN_DIM;
        sf[(i / IN_DIM) * 12 + c] = (n < N_NODES) ? LD(feat, (size_t)n * IN_DIM + c, f32) : 0.f;
    }
    __syncthreads();
    int ng = tid / 16, cg = tid % 16;
    float acc[4][4];
    #pragma unroll
    for (int i = 0; i < 4; i++)
        #pragma unroll
        for (int j = 0; j < 4; j++) acc[i][j] = sb0[cg * 4 + j];
    #pragma unroll
    for (int k = 0; k < IN_DIM; k++)
        #pragma unroll
        for (int i = 0; i < 4; i++) {
            float a = sf[(ng * 4 + i) * 12 + k];
            #pragma unroll
            for (int j = 0; j < 4; j++) acc[i][j] += a * sW0[k * 64 + cg * 4 + j];
        }
    #pragma unroll
    for (int i = 0; i < 4; i++)
        #pragma unroll
        for (int j = 0; j < 4; j++) sh[(ng * 4 + i) * 64 + cg * 4 + j] = fmaxf(acc[i][j], 0.f);
    __syncthreads();
    float o[4][4];
    #pragma unroll
    for (int i = 0; i < 4; i++)
        #pragma unroll
        for (int j = 0; j < 4; j++) o[i][j] = sb1[cg * 4 + j];
    for (int k = 0; k < 64; k++) {
        float4 bv = *(const float4*)&sW1[k * 64 + cg * 4];
        #pragma unroll
        for (int i = 0; i < 4; i++) {
            float a = sh[(ng * 4 + i) * 64 + k];
            o[i][0] += a * bv.x; o[i][1] += a * bv.y;
            o[i][2] += a * bv.z; o[i][3] += a * bv.w;
        }
    }
    #pragma unroll
    for (int i = 0; i < 4; i++) {
        int n = n0 + ng * 4 + i;
        if (n < N_NODES) {
            float* r = feats + (size_t)n * F_TOT;
            #pragma unroll
            for (int j = 0; j < 4; j++) r[IN_DIM + cg * 4 + j] = o[i][j];
        }
    }
    for (int i = tid; i < 64 * IN_DIM; i += 256) {
        int n = n0 + i / IN_DIM, c = i % IN_DIM;
        if (n < N_NODES) feats[(size_t)n * F_TOT + c] = sf[(i / IN_DIM) * 12 + c];
    }
}

// ---------------- fused edge tables ----------------------------------------
__global__ void k_tables(const void* __restrict__ etype_emb, const void* __restrict__ rid_emb,
                         const void* __restrict__ rc_W, const void* __restrict__ rc_b,
                         const void* __restrict__ rp_W, const void* __restrict__ rp_b,
                         const void* __restrict__ W_fij, const void* __restrict__ egat_bias,
                         float* __restrict__ T, const int* __restrict__ flagp) {
    const int f32 = *flagp;
    int l = blockIdx.x;
    __shared__ float S[NT_ROWS * HID];
    __shared__ float W[HID * HO];
    for (int i = threadIdx.x; i < 7 * HID; i += 256) S[i] = LD(etype_emb, i, f32);
    for (int i = threadIdx.x; i < 31 * HID; i += 256) S[7 * HID + i] = LD(rid_emb, i, f32);
    for (int i = threadIdx.x; i < 2 * HID; i += 256) S[38 * HID + i] = LD(rc_W, i, f32);
    for (int i = threadIdx.x; i < 3 * HID; i += 256) S[40 * HID + i] = LD(rp_W, i, f32);
    for (int i = threadIdx.x; i < HID; i += 256)
        S[43 * HID + i] = LD(rc_b, i, f32) + LD(rp_b, i, f32);
    for (int i = threadIdx.x; i < HID * HO; i += 256)
        W[i] = LD(W_fij, (size_t)l * HID * HO + i, f32);
    __syncthreads();
    for (int idx = threadIdx.x; idx < NT_ROWS * HO; idx += 256) {
        int r = idx / HO, c = idx % HO;
        float acc = (r == 43) ? LD(egat_bias, l * HO + c, f32) : 0.f;
        for (int k = 0; k < HID; k++) acc += S[r * HID + k] * W[k * HO + c];
        T[(size_t)l * NT_ROWS * HO + idx] = acc;
    }
}

// ---------------- node GEMMs via MFMA -> packed bf16 gather buffers --------
__global__ void __launch_bounds__(256) k_ngemm(
        const float* __restrict__ feats, int h_off,
        const unsigned short* __restrict__ pw_n, int l,
        unsigned* __restrict__ gsrc, unsigned* __restrict__ gdst) {
    __shared__ __align__(16) unsigned short Xs[64 * 72];
    __shared__ __align__(16) unsigned short Ws[384 * 72];
    int tid = threadIdx.x, n0 = blockIdx.x * 64;
    for (int i = tid; i < 64 * 64; i += 256) {
        int n = i >> 6, c = i & 63, gn = n0 + n;
        Xs[n * 72 + c] = rnebf((gn < N_NODES) ? feats[(size_t)gn * F_TOT + h_off + c] : 0.f);
    }
    const uint4* pn = (const uint4*)pw_n + (size_t)l * 3072;
    for (int i = tid; i < 3072; i += 256) {   // i = (m*128+c)*8 + kq
        int kq = i & 7, mc = i >> 3;
        *(uint4*)&Ws[mc * 72 + kq * 8] = pn[i];
    }
    __syncthreads();
    int wid = tid >> 6, lane = tid & 63;
    int row0 = wid * 16, mrow = lane & 15, quad = lane >> 4;
    bf16x8 a0 = *(const bf16x8*)&Xs[(row0 + mrow) * 72 + quad * 8];
    bf16x8 a1 = *(const bf16x8*)&Xs[(row0 + mrow) * 72 + 32 + quad * 8];
    f32x4 accA[8], accB[8];
    #pragma unroll
    for (int j = 0; j < 8; j++) { accA[j] = (f32x4){0,0,0,0}; accB[j] = (f32x4){0,0,0,0}; }
    #pragma unroll
    for (int j = 0; j < 8; j++) {
        bf16x8 b0 = *(const bf16x8*)&Ws[(0 * 128 + j * 16 + mrow) * 72 + quad * 8];
        bf16x8 b1 = *(const bf16x8*)&Ws[(0 * 128 + j * 16 + mrow) * 72 + 32 + quad * 8];
        accA[j] = __builtin_amdgcn_mfma_f32_16x16x32_bf16(a0, b0, accA[j], 0, 0, 0);
        accA[j] = __builtin_amdgcn_mfma_f32_16x16x32_bf16(a1, b1, accA[j], 0, 0, 0);
        bf16x8 c0 = *(const bf16x8*)&Ws[(2 * 128 + j * 16 + mrow) * 72 + quad * 8];
        bf16x8 c1 = *(const bf16x8*)&Ws[(2 * 128 + j * 16 + mrow) * 72 + 32 + quad * 8];
        accB[j] = __builtin_amdgcn_mfma_f32_16x16x32_bf16(a0, c0, accB[j], 0, 0, 0);
        accB[j] = __builtin_amdgcn_mfma_f32_16x16x32_bf16(a1, c1, accB[j], 0, 0, 0);
    }
    #pragma unroll
    for (int j = 0; j < 4; j++) {
        int c = j * 16 + mrow;
        #pragma unroll
        for (int r = 0; r < 4; r++) {
            int gn = n0 + row0 + quad * 4 + r;
            if (gn < N_NODES) {
                uint2 v;
                v.x = pk2(accA[j][r], accA[j + 4][r]);
                v.y = pk2(accB[j][r], accB[j + 4][r]);
                *(uint2*)&gsrc[(size_t)gn * 128 + c * 2] = v;
            }
        }
    }
    f32x4 accC[8];
    #pragma unroll
    for (int j = 0; j < 8; j++) accC[j] = (f32x4){0,0,0,0};
    #pragma unroll
    for (int j = 0; j < 8; j++) {
        bf16x8 b0 = *(const bf16x8*)&Ws[(1 * 128 + j * 16 + mrow) * 72 + quad * 8];
        bf16x8 b1 = *(const bf16x8*)&Ws[(1 * 128 + j * 16 + mrow) * 72 + 32 + quad * 8];
        accC[j] = __builtin_amdgcn_mfma_f32_16x16x32_bf16(a0, b0, accC[j], 0, 0, 0);
        accC[j] = __builtin_amdgcn_mfma_f32_16x16x32_bf16(a1, b1, accC[j], 0, 0, 0);
    }
    #pragma unroll
    for (int j = 0; j < 4; j++) {
        int c = j * 16 + mrow;
        #pragma unroll
        for (int r = 0; r < 4; r++) {
            int gn = n0 + row0 + quad * 4 + r;
            if (gn < N_NODES)
                gdst[(size_t)gn * 64 + c] = pk2(accC[j][r], accC[j + 4][r]);
        }
    }
}

// ---------------- fused edge phase -----------------------------------------
// Round-10: 4-deep PREDICATED pipeline. Round-9's serial tail (deg mod 4 ~= 1.5
// edges/node, each a full ~200-cycle dependency chain) was the regression; now
// every edge goes through the 4-wide pipelined path and the last partial group
// is masked (w=0 contributes exact +0.0 to Lsp/A2 -> bit-identical numerics).
// Fetch indices are clamped (min with last) so padded slots re-read a valid
// edge from L2 instead of branching.
__global__ void __launch_bounds__(256) k_edge_fused(
        const float* __restrict__ T, const void* __restrict__ attn, int l,
        const unsigned* __restrict__ gsrc, const unsigned* __restrict__ gdst,
        const int* __restrict__ rowptr, const uint4* __restrict__ emeta,
        float* __restrict__ h_att, const int* __restrict__ flagp) {
    const int f32 = *flagp;
    __shared__ f32x2 Ts2[38 * 64];          // [row][lane] = {head0, head1}
    const float* Tl = T + (size_t)l * NT_ROWS * HO;
    int tid = threadIdx.x;
    for (int i = tid; i < 38 * 64; i += 256) {
        int r = i >> 6, c = i & 63;
        Ts2[i] = (f32x2){Tl[r * HO + c], Tl[r * HO + 64 + c]};
    }
    int lane = tid & 63;
    f32x2 C2[6];
    #pragma unroll
    for (int r = 0; r < 6; r++)
        C2[r] = (f32x2){Tl[(38 + r) * HO + lane], Tl[(38 + r) * HO + 64 + lane]};
    f32x2 AT2 = (f32x2){LD(attn, l * HO + lane, f32), LD(attn, l * HO + 64 + lane, f32)};
    __syncthreads();
    int wid = tid >> 6;
    int d0 = blockIdx.x * 8 + wid * 2;

    #pragma unroll 1
    for (int dn = 0; dn < 2; dn++) {
        int d = d0 + dn;
        int jb = rowptr[d], je = rowptr[d + 1];
        // clamp target for padded fetches: valid for deg-0 nodes and end-of-array
        int last = je - 1;
        if (last < jb) last = jb;
        if (last > N_EDGES - 1) last = N_EDGES - 1;
        unsigned gd = gdst[(size_t)d * 64 + lane];
        f32x2 NJ2 = up2(gd) + C2[5];         // const row folded in
        f32x2 A2 = (f32x2){0.f, 0.f};
        float Lsp = 0.f;                     // split-space denominator

        // -> s_out: head0 sum in lanes 0-31, head1 sum in lanes 32-63 (pre-exp)
        auto logits = [&](const uint4& em, const uint2& g, float& s_out, f32x2& h2) {
            unsigned w = em.w;
            int et = (int)(w & 7u), ri = (int)((w >> 3) & 31u);
            f32x2 x = up2(g.x) + NJ2;
            x += Ts2[et * 64 + lane];
            x += Ts2[(7 + ri) * 64 + lane];
            x += plo(em.x) * C2[0];
            x += phi(em.x) * C2[1];
            x += plo(em.y) * C2[2];
            x += phi(em.y) * C2[3];
            x += plo(em.z) * C2[4];
            f32x2 xs = x * NEG_SLOPE;        // leaky = max(x, 0.2x) for slope<1
            x.x = fmaxf(x.x, xs.x);
            x.y = fmaxf(x.y, xs.y);
            f32x2 p = x * AT2;
            h2 = up2(g.y);
            float pa = p.x, pb = p.y;
            pswap(pa, pb);                   // pa=[p0_lo|p1_lo], pb=[p0_hi|p1_hi]
            float s = pa + pb;               // lanes 0-31: head0, 32-63: head1
            s += __int_as_float(__builtin_amdgcn_update_dpp(0, __float_as_int(s), 0xB1, 0xF, 0xF, true));
            s += __int_as_float(__builtin_amdgcn_update_dpp(0, __float_as_int(s), 0x4E, 0xF, 0xF, true));
            s += __int_as_float(__builtin_amdgcn_update_dpp(0, __float_as_int(s), 0x141, 0xF, 0xF, true));
            s += __int_as_float(__builtin_amdgcn_update_dpp(0, __float_as_int(s), 0x140, 0xF, 0xF, true));
            s += __int_as_float(__builtin_amdgcn_ds_swizzle(__float_as_int(s), 0x401F));
            s_out = s;
        };
        auto update = [&](float w, f32x2 h2) {   // takes pre-masked weight
            Lsp += w;
            float wa = w, wb = w;
            pswap(wa, wb);                   // wa = w0 all lanes, wb = w1 all lanes
            A2 += (f32x2){wa, wb} * h2;
        };
        auto fetch = [&](int j_, uint4& em, uint2& g) {
            int jj = (j_ < last) ? j_ : last;    // branch-free clamp
            em = emeta[jj];
            g = *(const uint2*)&gsrc[(size_t)(em.w >> 8) * 128 + lane * 2];
        };

        uint4 emA, emB, emC, emD;
        uint2 gA, gB, gC, gD;
        fetch(jb,     emA, gA);
        fetch(jb + 1, emB, gB);
        fetch(jb + 2, emC, gC);
        fetch(jb + 3, emD, gD);
        #pragma unroll 1
        for (int j = jb; j < je; j += 4) {
            float sA, sB, sC, sD;
            f32x2 hA, hB, hC, hD;
            logits(emA, gA, sA, hA);         // 4 independent chains
            logits(emB, gB, sB, hB);
            logits(emC, gC, sC, hC);
            logits(emD, gD, sD, hD);
            float wA = __expf(sA);                            // j < je always
            float wB = (j + 1 < je) ? __expf(sB) : 0.f;       // wave-uniform masks
            float wC = (j + 2 < je) ? __expf(sC) : 0.f;
            float wD = (j + 3 < je) ? __expf(sD) : 0.f;
            if (j + 4 < je) {                // uniform branch: skip dead prefetch
                fetch(j + 4, emA, gA);
                fetch(j + 5, emB, gB);
                fetch(j + 6, emC, gC);
                fetch(j + 7, emD, gD);
            }
            update(wA, hA);
            update(wB, hB);
            update(wC, hC);
            update(wD, hD);
        }

        float la = Lsp, lb = Lsp;
        pswap(la, lb);                       // la = L0 all lanes, lb = L1 all lanes
        h_att[(size_t)d * HO + lane]      = A2.x / (la + 1e-9f);
        h_att[(size_t)d * HO + 64 + lane] = A2.y / (lb + 1e-9f);
    }
}

// ---------------- node MLP + residual via MFMA ------------------------------
__global__ void __launch_bounds__(256) k_mlp(
        const float* __restrict__ h_att,
        const unsigned short* __restrict__ pw_m0, const void* __restrict__ bm0,
        const unsigned short* __restrict__ pw_m1, const void* __restrict__ bm1, int l,
        float* __restrict__ feats, int prev_off, int out_off,
        const int* __restrict__ flagp) {
    const int f32 = *flagp;
    __shared__ __align__(16) unsigned short Xs[64 * 136];
    __shared__ __align__(16) unsigned short W0T[128 * 136];
    __shared__ __align__(16) unsigned short W1T[64 * 136];
    __shared__ float sb0[HO], sb1[64];
    int tid = threadIdx.x, n0 = blockIdx.x * 64;
    for (int i = tid; i < 64 * 128; i += 256) {
        int n = i >> 7, c = i & 127, gn = n0 + n;
        Xs[n * 136 + c] = rnebf((gn < N_NODES) ? h_att[(size_t)gn * HO + c] : 0.f);
    }
    const uint4* p0 = (const uint4*)pw_m0 + (size_t)l * 2048;
    for (int i = tid; i < 2048; i += 256) {   // i = c*16 + kq
        int kq = i & 15, c = i >> 4;
        *(uint4*)&W0T[c * 136 + kq * 8] = p0[i];
    }
    const uint4* p1 = (const uint4*)pw_m1 + (size_t)l * 1024;
    for (int i = tid; i < 1024; i += 256) {
        int kq = i & 15, c = i >> 4;
        *(uint4*)&W1T[c * 136 + kq * 8] = p1[i];
    }
    for (int i = tid; i < HO; i += 256) sb0[i] = LD(bm0, l * HO + i, f32);
    for (int i = tid; i < 64; i += 256) sb1[i] = LD(bm1, l * 64 + i, f32);
    __syncthreads();
    int wid = tid >> 6, lane = tid & 63;
    int row0 = wid * 16, mrow = lane & 15, quad = lane >> 4;
    f32x4 acc[8];
    #pragma unroll
    for (int j = 0; j < 8; j++) {
        float b = sb0[j * 16 + mrow];
        acc[j] = (f32x4){b, b, b, b};
    }
    #pragma unroll
    for (int ks = 0; ks < 4; ks++) {
        bf16x8 a = *(const bf16x8*)&Xs[(row0 + mrow) * 136 + ks * 32 + quad * 8];
        #pragma unroll
        for (int j = 0; j < 8; j++) {
            bf16x8 b = *(const bf16x8*)&W0T[(j * 16 + mrow) * 136 + ks * 32 + quad * 8];
            acc[j] = __builtin_amdgcn_mfma_f32_16x16x32_bf16(a, b, acc[j], 0, 0, 0);
        }
    }
    #pragma unroll
    for (int j = 0; j < 8; j++)
        #pragma unroll
        for (int r = 0; r < 4; r++)
            Xs[(row0 + quad * 4 + r) * 136 + j * 16 + mrow] = rnebf(fmaxf(acc[j][r], 0.f));
    f32x4 o[4];
    #pragma unroll
    for (int j = 0; j < 4; j++) {
        float b = sb1[j * 16 + mrow];
        o[j] = (f32x4){b, b, b, b};
    }
    #pragma unroll
    for (int ks = 0; ks < 4; ks++) {
        bf16x8 a = *(const bf16x8*)&Xs[(row0 + mrow) * 136 + ks * 32 + quad * 8];
        #pragma unroll
        for (int j = 0; j < 4; j++) {
            bf16x8 b = *(const bf16x8*)&W1T[(j * 16 + mrow) * 136 + ks * 32 + quad * 8];
            o[j] = __builtin_amdgcn_mfma_f32_16x16x32_bf16(a, b, o[j], 0, 0, 0);
        }
    }
    #pragma unroll
    for (int j = 0; j < 4; j++) {
        int c = j * 16 + mrow;
        #pragma unroll
        for (int r = 0; r < 4; r++) {
            int gn = n0 + row0 + quad * 4 + r;
            if (gn < N_NODES) {
                float* rw = feats + (size_t)gn * F_TOT;
                rw[out_off + c] = o[j][r] + rw[prev_off + c];
            }
        }
    }
}

// ---------------- graph max pool -------------------------------------------
__global__ void k_pool(const float* __restrict__ feats, unsigned* __restrict__ gmax) {
    int g = blockIdx.x;
    int chunk = blockIdx.y;
    int t = threadIdx.x;
    const int CS = 49;
    int nb = chunk * CS;
    int ne = (nb + CS < NPG) ? nb + CS : NPG;
    float m0 = -INFINITY, m1 = -INFINITY;
    for (int n = nb; n < ne; n++) {
        const float* row = feats + (size_t)(g * NPG + n) * F_TOT;
        m0 = fmaxf(m0, row[t]);
        if (t + 256 < F_TOT) m1 = fmaxf(m1, row[t + 256]);
    }
    atomicMax(&gmax[g * F_TOT + t], fkey(m0));
    if (t + 256 < F_TOT) atomicMax(&gmax[g * F_TOT + t + 256], fkey(m1));
}

// ---------------- output write: wave per row --------------------------------
__global__ void k_out(const float* __restrict__ feats, const unsigned* __restrict__ gmax,
                      void* __restrict__ out, const int* __restrict__ flagp) {
    const int f32 = *flagp;
    int lane = threadIdx.x & 63;
    int wave = (blockIdx.x * blockDim.x + threadIdx.x) >> 6;
    int nw = (gridDim.x * blockDim.x) >> 6;
    for (int row = wave; row < B_GRAPHS * NPG; row += nw) {
        int g = row / NPG;
        const float* fr = feats + (size_t)row * F_TOT;
        const unsigned* gr = gmax + g * F_TOT;
        if (f32) {
            float* o = (float*)out + (size_t)row * OUT_C;
            for (int c = lane; c < OUT_C; c += 64)
                o[c] = (c < F_TOT) ? fr[c] : funkey(gr[c - F_TOT]);
        } else {
            __hip_bfloat16* o = (__hip_bfloat16*)out + (size_t)row * OUT_C;
            for (int c = lane; c < OUT_C; c += 64)
                o[c] = __float2bfloat16((c < F_TOT) ? fr[c] : funkey(gr[c - F_TOT]));
        }
    }
}

extern "C" void kernel_launch(void* const* d_in, const int* in_sizes, int n_in,
                              void* d_out, int out_size, void* d_ws, size_t ws_size,
                              hipStream_t stream) {
    const void* feat      = d_in[0];
    const void* att_rc    = d_in[1];
    const void* att_rp    = d_in[2];
    const void* etype_emb = d_in[3];
    const void* rid_emb   = d_in[4];
    const void* rc_W      = d_in[5];
    const void* rc_b      = d_in[6];
    const void* rp_W      = d_in[7];
    const void* rp_b      = d_in[8];
    const void* fe_W0     = d_in[9];
    const void* fe_b0     = d_in[10];
    const void* fe_W1     = d_in[11];
    const void* fe_b1     = d_in[12];
    const void* W_ni      = d_in[13];
    const void* W_nj      = d_in[14];
    const void* W_fij     = d_in[15];
    const void* W_node    = d_in[16];
    const void* attn      = d_in[17];
    const void* egat_bias = d_in[18];
    const void* Wm0       = d_in[19];
    const void* bm0       = d_in[20];
    const void* Wm1       = d_in[21];
    const void* bm1       = d_in[22];
    const int* src   = (const int*)d_in[23];
    const int* dst   = (const int*)d_in[24];
    const int* etype = (const int*)d_in[25];
    const int* rid   = (const int*)d_in[26];

    char* p = (char*)d_ws;
    auto alloc = [&](size_t bytes) {
        char* r = p;
        p += (bytes + 255) & ~(size_t)255;
        return r;
    };
    float*    feats  = (float*)alloc((size_t)N_NODES * F_TOT * 4);
    unsigned* gsrc   = (unsigned*)alloc((size_t)N_NODES * HO * 4);
    unsigned* gdst   = (unsigned*)alloc((size_t)N_NODES * 64 * 4);
    float*    h_att  = (float*)alloc((size_t)N_NODES * HO * 4);
    float*    T      = (float*)alloc((size_t)3 * NT_ROWS * HO * 4);
    unsigned* gmax   = (unsigned*)alloc((size_t)B_GRAPHS * F_TOT * 4);
    int*      flagp  = (int*)alloc(256);
    int*      rowptr = (int*)alloc((size_t)(N_NODES + 1) * 4);
    int*      cursor = (int*)alloc((size_t)N_NODES * 4);
    int*      cnt    = (int*)alloc((size_t)N_NODES * 4);
    int*      bsum   = (int*)alloc((size_t)SCB * 4);
    int*      boff   = (int*)alloc((size_t)SCB * 4);
    uint4*    emeta  = (uint4*)alloc((size_t)N_EDGES * 16);
    unsigned short* pw_n  = (unsigned short*)alloc((size_t)73728 * 2);
    unsigned short* pw_m0 = (unsigned short*)alloc((size_t)49152 * 2);
    unsigned short* pw_m1 = (unsigned short*)alloc((size_t)24576 * 2);

    k_detect<<<1, 256, 0, stream>>>(att_rc, flagp);
    hipMemsetAsync(cnt, 0, (size_t)N_NODES * 4, stream);
    hipMemsetAsync(gmax, 0, (size_t)B_GRAPHS * F_TOT * 4, stream);
    k_wprep<<<576, 256, 0, stream>>>(W_ni, W_nj, W_node, Wm0, Wm1,
                                     pw_n, pw_m0, pw_m1, flagp);
    k_count<<<512, 256, 0, stream>>>(dst, cnt);
    k_scan1<<<SCB, 256, 0, stream>>>(cnt, bsum);
    k_scan2<<<1, 256, 0, stream>>>(bsum, boff);
    k_scan3<<<SCB, 256, 0, stream>>>(cnt, boff, rowptr, cursor);
    k_fill<<<1024, 256, 0, stream>>>(src, dst, etype, rid, att_rc, att_rp,
                                     cursor, emeta, flagp);
    k_init<<<(N_NODES + 63) / 64, 256, 0, stream>>>(feat, fe_W0, fe_b0, fe_W1, fe_b1,
                                                    feats, flagp);
    k_tables<<<3, 256, 0, stream>>>(etype_emb, rid_emb, rc_W, rc_b, rp_W, rp_b,
                                    W_fij, egat_bias, T, flagp);
    for (int l = 0; l < 3; l++) {
        int h_off = IN_DIM + l * HID;
        int out_off = IN_DIM + (l + 1) * HID;
        k_ngemm<<<(N_NODES + 63) / 64, 256, 0, stream>>>(feats, h_off, pw_n, l, gsrc, gdst);
        k_edge_fused<<<N_NODES / 8, 256, 0, stream>>>(T, attn, l, gsrc, gdst,
                                                      rowptr, emeta, h_att, flagp);
        k_mlp<<<(N_NODES + 63) / 64, 256, 0, stream>>>(h_att, pw_m0, bm0, pw_m1, bm1, l,
                                                       feats, h_off, out_off, flagp);
    }
    k_pool<<<dim3(B_GRAPHS, 128), 256, 0, stream>>>(feats, gmax);
    k_out<<<2048, 256, 0, stream>>>(feats, gmax, d_out, flagp);
}

// Round 5
// 720.135 us; speedup vs baseline: 1.1659x; 1.0489x over previous
//
#include <hip/hip_runtime.h>
#include <hip/hip_bf16.h>
#include <math.h>

#define N_NODES 50000
#define N_EDGES 500000
#define B_GRAPHS 8
#define NPG 6250
#define HID 64
#define HO 128          // HEADS*HID
#define IN_DIM 10
#define F_TOT 266       // IN_DIM + 4*HID
#define OUT_C 532       // 2*F_TOT
#define NEG_SLOPE 0.2f
#define NT_ROWS 44      // 7 etype + 31 rid + 2 rc + 3 rp + 1 const
#define SCB 200         // scan blocks
#define SCH 250         // scan chunk (SCB*SCH == N_NODES)

typedef short bf16x8 __attribute__((ext_vector_type(8)));
typedef float f32x4 __attribute__((ext_vector_type(4)));
typedef float f32x2 __attribute__((ext_vector_type(2)));
typedef unsigned u32x2v __attribute__((ext_vector_type(2)));

// dtype-agnostic float load: f32 flag chooses fp32 or bf16 interpretation
__device__ __forceinline__ float LD(const void* p, size_t i, int f32) {
    if (f32) return ((const float*)p)[i];
    unsigned u = ((const unsigned short*)p)[i];
    return __uint_as_float(u << 16);
}
__device__ __forceinline__ unsigned fkey(float f) {
    unsigned b = __float_as_uint(f);
    return (b & 0x80000000u) ? ~b : (b | 0x80000000u);
}
__device__ __forceinline__ float funkey(unsigned k) {
    unsigned b = (k & 0x80000000u) ? (k & 0x7fffffffu) : ~k;
    return __uint_as_float(b);
}
__device__ __forceinline__ unsigned short rnebf(float x) {
    unsigned u = __float_as_uint(x);
    return (unsigned short)((u + 0x7FFFu + ((u >> 16) & 1u)) >> 16);
}
__device__ __forceinline__ unsigned pk2(float lo, float hi) {
    return (unsigned)rnebf(lo) | ((unsigned)rnebf(hi) << 16);
}
__device__ __forceinline__ float plo(unsigned u) { return __uint_as_float(u << 16); }
__device__ __forceinline__ float phi(unsigned u) { return __uint_as_float(u & 0xFFFF0000u); }
// unpack a (lo,hi) bf16 pair to float2
__device__ __forceinline__ f32x2 up2(unsigned u) {
    return (f32x2){__uint_as_float(u << 16), __uint_as_float(u & 0xFFFF0000u)};
}
// half-wave swap via the backend-modeled intrinsic (NOT inline asm: two "+v"
// asm operands fed the same value can be register-coalesced into ONE VGPR,
// turning the swap into v_permlane32_swap v5,v5 — the round-2 correctness bug).
// after pswap(a,b): a = [a_lo|b_lo], b = [a_hi|b_hi]
__device__ __forceinline__ void pswap(float& a, float& b) {
    u32x2v r = __builtin_amdgcn_permlane32_swap(__float_as_uint(a), __float_as_uint(b),
                                                false, false);
    a = __uint_as_float(r.x);
    b = __uint_as_float(r.y);
}

// ---------------- dtype detection ------------------------------------------
__global__ void k_detect(const void* __restrict__ att_rc, int* __restrict__ flagp) {
    __shared__ int cnt;
    if (threadIdx.x == 0) cnt = 0;
    __syncthreads();
    const unsigned short* w = (const unsigned short*)att_rc;
    int c = 0;
    for (int i = threadIdx.x; i < 8192; i += 256) {
        unsigned e = (w[i] >> 7) & 0xFF;
        if (e >= 0xC0) c++;
    }
    atomicAdd(&cnt, c);
    __syncthreads();
    if (threadIdx.x == 0) *flagp = (cnt > 8) ? 1 : 0;
}

// ---------------- weight pre-pack to bf16 (transposed LDS layouts) ----------
// pw_n[((l*3+m)*128+c)*64+k], pw_m0[(l*128+c)*128+k], pw_m1[(l*64+c)*128+k]
__global__ void k_wprep(const void* __restrict__ W_ni, const void* __restrict__ W_nj,
                        const void* __restrict__ W_node, const void* __restrict__ Wm0,
                        const void* __restrict__ Wm1,
                        unsigned short* __restrict__ pw_n,
                        unsigned short* __restrict__ pw_m0,
                        unsigned short* __restrict__ pw_m1,
                        const int* __restrict__ flagp) {
    const int f32 = *flagp;
    int i = blockIdx.x * 256 + threadIdx.x;
    if (i < 73728) {                      // 3l x 3m x 128c x 64k
        int k = i & 63, c = (i >> 6) & 127, lm = i >> 13;
        int m = lm % 3, l = lm / 3;
        const void* W = (m == 0) ? W_ni : (m == 1) ? W_nj : W_node;
        pw_n[i] = rnebf(LD(W, (size_t)l * 8192 + k * 128 + c, f32));
    } else if (i < 73728 + 49152) {       // 3l x 128c x 128k
        int j = i - 73728;
        int k = j & 127, c = (j >> 7) & 127, l = j >> 14;
        pw_m0[j] = rnebf(LD(Wm0, (size_t)l * 16384 + k * 128 + c, f32));
    } else if (i < 147456) {              // 3l x 64c x 128k
        int j = i - 122880;
        int k = j & 127, c = (j >> 7) & 63, l = j >> 13;
        pw_m1[j] = rnebf(LD(Wm1, (size_t)l * 8192 + k * 64 + c, f32));
    }
}

// ---------------- CSR build ------------------------------------------------
__global__ void k_count(const int* __restrict__ dst, int* __restrict__ cnt) {
    int i = blockIdx.x * blockDim.x + threadIdx.x;
    int stride = gridDim.x * blockDim.x;
    for (int e = i; e < N_EDGES; e += stride) atomicAdd(&cnt[dst[e]], 1);
}

__global__ void k_scan1(const int* __restrict__ cnt, int* __restrict__ bsum) {
    __shared__ int red[256];
    int b = blockIdx.x, t = threadIdx.x;
    red[t] = (t < SCH) ? cnt[b * SCH + t] : 0;
    __syncthreads();
    for (int off = 128; off; off >>= 1) {
        if (t < off) red[t] += red[t + off];
        __syncthreads();
    }
    if (t == 0) bsum[b] = red[0];
}
__global__ void k_scan2(const int* __restrict__ bsum, int* __restrict__ boff) {
    __shared__ int ts[256];
    int t = threadIdx.x;
    int v = (t < SCB) ? bsum[t] : 0;
    ts[t] = v;
    __syncthreads();
    for (int off = 1; off < 256; off <<= 1) {
        int u = (t >= off) ? ts[t - off] : 0;
        __syncthreads();
        ts[t] += u;
        __syncthreads();
    }
    if (t < SCB) boff[t] = ts[t] - v;
}
__global__ void k_scan3(const int* __restrict__ cnt, const int* __restrict__ boff,
                        int* __restrict__ rowptr, int* __restrict__ cursor) {
    __shared__ int ts[256];
    int b = blockIdx.x, t = threadIdx.x;
    int base = b * SCH;
    int v = (t < SCH) ? cnt[base + t] : 0;
    ts[t] = v;
    __syncthreads();
    for (int off = 1; off < 256; off <<= 1) {
        int u = (t >= off) ? ts[t - off] : 0;
        __syncthreads();
        ts[t] += u;
        __syncthreads();
    }
    if (t < SCH) {
        int r = boff[b] + ts[t] - v;
        rowptr[base + t] = r;
        cursor[base + t] = r;
    }
    if (b == SCB - 1 && t == SCH - 1) rowptr[N_NODES] = boff[b] + ts[t];
}

// emeta.w = etype | rid<<3 | src<<8   (src < 65536)
__global__ void k_fill(const int* __restrict__ src, const int* __restrict__ dst,
                       const int* __restrict__ etype, const int* __restrict__ rid,
                       const void* __restrict__ att_rc, const void* __restrict__ att_rp,
                       int* __restrict__ cursor, uint4* __restrict__ emeta,
                       const int* __restrict__ flagp) {
    const int f32 = *flagp;
    int i = blockIdx.x * blockDim.x + threadIdx.x;
    int stride = gridDim.x * blockDim.x;
    for (int e = i; e < N_EDGES; e += stride) {
        int d = dst[e];
        int j = atomicAdd(&cursor[d], 1);
        float rc0 = LD(att_rc, 2 * (size_t)e, f32), rc1 = LD(att_rc, 2 * (size_t)e + 1, f32);
        float rp0 = LD(att_rp, 3 * (size_t)e, f32), rp1 = LD(att_rp, 3 * (size_t)e + 1, f32),
              rp2 = LD(att_rp, 3 * (size_t)e + 2, f32);
        uint4 m;
        m.x = pk2(rc0, rc1);
        m.y = pk2(rp0, rp1);
        m.z = pk2(rp2, 0.f);
        m.w = (unsigned)(etype[e] | (rid[e] << 3) | ((unsigned)src[e] << 8));
        emeta[j] = m;
    }
}

// ---------------- initial feature MLP --------------------------------------
__global__ void k_init(const void* __restrict__ feat,
                       const void* __restrict__ W0, const void* __restrict__ b0,
                       const void* __restrict__ W1, const void* __restrict__ b1,
                       float* __restrict__ feats, const int* __restrict__ flagp) {
    const int f32 = *flagp;
    __shared__ float sf[64 * 12];
    __shared__ float sW0[IN_DIM * 64];
    __shared__ float sb0[64], sb1[64];
    __shared__ float sh[64 * 64];
    __shared__ float sW1[64 * 64];
    int tid = threadIdx.x, n0 = blockIdx.x * 64;
    for (int i = tid; i < IN_DIM * 64; i += 256) sW0[i] = LD(W0, i, f32);
    for (int i = tid; i < 64; i += 256) { sb0[i] = LD(b0, i, f32); sb1[i] = LD(b1, i, f32); }
    for (int i = tid; i < 64 * 64; i += 256) sW1[i] = LD(W1, i, f32);
    for (int i = tid; i < 64 * IN_DIM; i += 256) {
        int n = n0 + i / IN_DIM, c = i % IN_DIM;
        sf[(i / IN_DIM) * 12 + c] = (n < N_NODES) ? LD(feat, (size_t)n * IN_DIM + c, f32) : 0.f;
    }
    __syncthreads();
    int ng = tid / 16, cg = tid % 16;
    float acc[4][4];
    #pragma unroll
    for (int i = 0; i < 4; i++)
        #pragma unroll
        for (int j = 0; j < 4; j++) acc[i][j] = sb0[cg * 4 + j];
    #pragma unroll
    for (int k = 0; k < IN_DIM; k++)
        #pragma unroll
        for (int i = 0; i < 4; i++) {
            float a = sf[(ng * 4 + i) * 12 + k];
            #pragma unroll
            for (int j = 0; j < 4; j++) acc[i][j] += a * sW0[k * 64 + cg * 4 + j];
        }
    #pragma unroll
    for (int i = 0; i < 4; i++)
        #pragma unroll
        for (int j = 0; j < 4; j++) sh[(ng * 4 + i) * 64 + cg * 4 + j] = fmaxf(acc[i][j], 0.f);
    __syncthreads();
    float o[4][4];
    #pragma unroll
    for (int i = 0; i < 4; i++)
        #pragma unroll
        for (int j = 0; j < 4; j++) o[i][j] = sb1[cg * 4 + j];
    for (int k = 0; k < 64; k++) {
        float4 bv = *(const float4*)&sW1[k * 64 + cg * 4];
        #pragma unroll
        for (int i = 0; i < 4; i++) {
            float a = sh[(ng * 4 + i) * 64 + k];
            o[i][0] += a * bv.x; o[i][1] += a * bv.y;
            o[i][2] += a * bv.z; o[i][3] += a * bv.w;
        }
    }
    #pragma unroll
    for (int i = 0; i < 4; i++) {
        int n = n0 + ng * 4 + i;
        if (n < N_NODES) {
            float* r = feats + (size_t)n * F_TOT;
            #pragma unroll
            for (int j = 0; j < 4; j++) r[IN_DIM + cg * 4 + j] = o[i][j];
        }
    }
    for (int i = tid; i < 64 * IN_DIM; i += 256) {
        int n = n0 + i / IN_DIM, c = i % IN_DIM;
        if (n < N_NODES) feats[(size_t)n * F_TOT + c] = sf[(i / IN_DIM) * 12 + c];
    }
}

// ---------------- fused edge tables ----------------------------------------
__global__ void k_tables(const void* __restrict__ etype_emb, const void* __restrict__ rid_emb,
                         const void* __restrict__ rc_W, const void* __restrict__ rc_b,
                         const void* __restrict__ rp_W, const void* __restrict__ rp_b,
                         const void* __restrict__ W_fij, const void* __restrict__ egat_bias,
                         float* __restrict__ T, const int* __restrict__ flagp) {
    const int f32 = *flagp;
    int l = blockIdx.x;
    __shared__ float S[NT_ROWS * HID];
    __shared__ float W[HID * HO];
    for (int i = threadIdx.x; i < 7 * HID; i += 256) S[i] = LD(etype_emb, i, f32);
    for (int i = threadIdx.x; i < 31 * HID; i += 256) S[7 * HID + i] = LD(rid_emb, i, f32);
    for (int i = threadIdx.x; i < 2 * HID; i += 256) S[38 * HID + i] = LD(rc_W, i, f32);
    for (int i = threadIdx.x; i < 3 * HID; i += 256) S[40 * HID + i] = LD(rp_W, i, f32);
    for (int i = threadIdx.x; i < HID; i += 256)
        S[43 * HID + i] = LD(rc_b, i, f32) + LD(rp_b, i, f32);
    for (int i = threadIdx.x; i < HID * HO; i += 256)
        W[i] = LD(W_fij, (size_t)l * HID * HO + i, f32);
    __syncthreads();
    for (int idx = threadIdx.x; idx < NT_ROWS * HO; idx += 256) {
        int r = idx / HO, c = idx % HO;
        float acc = (r == 43) ? LD(egat_bias, l * HO + c, f32) : 0.f;
        for (int k = 0; k < HID; k++) acc += S[r * HID + k] * W[k * HO + c];
        T[(size_t)l * NT_ROWS * HO + idx] = acc;
    }
}

// ---------------- node GEMMs via MFMA -> packed bf16 gather buffers --------
__global__ void __launch_bounds__(256) k_ngemm(
        const float* __restrict__ feats, int h_off,
        const unsigned short* __restrict__ pw_n, int l,
        unsigned* __restrict__ gsrc, unsigned* __restrict__ gdst) {
    __shared__ __align__(16) unsigned short Xs[64 * 72];
    __shared__ __align__(16) unsigned short Ws[384 * 72];
    int tid = threadIdx.x, n0 = blockIdx.x * 64;
    for (int i = tid; i < 64 * 64; i += 256) {
        int n = i >> 6, c = i & 63, gn = n0 + n;
        Xs[n * 72 + c] = rnebf((gn < N_NODES) ? feats[(size_t)gn * F_TOT + h_off + c] : 0.f);
    }
    const uint4* pn = (const uint4*)pw_n + (size_t)l * 3072;
    for (int i = tid; i < 3072; i += 256) {   // i = (m*128+c)*8 + kq
        int kq = i & 7, mc = i >> 3;
        *(uint4*)&Ws[mc * 72 + kq * 8] = pn[i];
    }
    __syncthreads();
    int wid = tid >> 6, lane = tid & 63;
    int row0 = wid * 16, mrow = lane & 15, quad = lane >> 4;
    bf16x8 a0 = *(const bf16x8*)&Xs[(row0 + mrow) * 72 + quad * 8];
    bf16x8 a1 = *(const bf16x8*)&Xs[(row0 + mrow) * 72 + 32 + quad * 8];
    f32x4 accA[8], accB[8];
    #pragma unroll
    for (int j = 0; j < 8; j++) { accA[j] = (f32x4){0,0,0,0}; accB[j] = (f32x4){0,0,0,0}; }
    #pragma unroll
    for (int j = 0; j < 8; j++) {
        bf16x8 b0 = *(const bf16x8*)&Ws[(0 * 128 + j * 16 + mrow) * 72 + quad * 8];
        bf16x8 b1 = *(const bf16x8*)&Ws[(0 * 128 + j * 16 + mrow) * 72 + 32 + quad * 8];
        accA[j] = __builtin_amdgcn_mfma_f32_16x16x32_bf16(a0, b0, accA[j], 0, 0, 0);
        accA[j] = __builtin_amdgcn_mfma_f32_16x16x32_bf16(a1, b1, accA[j], 0, 0, 0);
        bf16x8 c0 = *(const bf16x8*)&Ws[(2 * 128 + j * 16 + mrow) * 72 + quad * 8];
        bf16x8 c1 = *(const bf16x8*)&Ws[(2 * 128 + j * 16 + mrow) * 72 + 32 + quad * 8];
        accB[j] = __builtin_amdgcn_mfma_f32_16x16x32_bf16(a0, c0, accB[j], 0, 0, 0);
        accB[j] = __builtin_amdgcn_mfma_f32_16x16x32_bf16(a1, c1, accB[j], 0, 0, 0);
    }
    #pragma unroll
    for (int j = 0; j < 4; j++) {
        int c = j * 16 + mrow;
        #pragma unroll
        for (int r = 0; r < 4; r++) {
            int gn = n0 + row0 + quad * 4 + r;
            if (gn < N_NODES) {
                uint2 v;
                v.x = pk2(accA[j][r], accA[j + 4][r]);
                v.y = pk2(accB[j][r], accB[j + 4][r]);
                *(uint2*)&gsrc[(size_t)gn * 128 + c * 2] = v;
            }
        }
    }
    f32x4 accC[8];
    #pragma unroll
    for (int j = 0; j < 8; j++) accC[j] = (f32x4){0,0,0,0};
    #pragma unroll
    for (int j = 0; j < 8; j++) {
        bf16x8 b0 = *(const bf16x8*)&Ws[(1 * 128 + j * 16 + mrow) * 72 + quad * 8];
        bf16x8 b1 = *(const bf16x8*)&Ws[(1 * 128 + j * 16 + mrow) * 72 + 32 + quad * 8];
        accC[j] = __builtin_amdgcn_mfma_f32_16x16x32_bf16(a0, b0, accC[j], 0, 0, 0);
        accC[j] = __builtin_amdgcn_mfma_f32_16x16x32_bf16(a1, b1, accC[j], 0, 0, 0);
    }
    #pragma unroll
    for (int j = 0; j < 4; j++) {
        int c = j * 16 + mrow;
        #pragma unroll
        for (int r = 0; r < 4; r++) {
            int gn = n0 + row0 + quad * 4 + r;
            if (gn < N_NODES)
                gdst[(size_t)gn * 64 + c] = pk2(accC[j][r], accC[j + 4][r]);
        }
    }
}

// ---------------- fused edge phase -----------------------------------------
// Round-11: (a) em loads scalarized (readfirstlane-forced uniform index ->
// s_load_dwordx4 into SGPRs; et/ri/feature unpacks + gather addr move to the
// SALU pipe, freeing ~10 VALU issues/edge); (b) 2-phase unrolled pipeline:
// em prefetched 2 groups ahead, gather g 1 full group ahead (~250-400 cy
// issue-to-use, covers L2/L3 miss latency); (c) attn pre-scaled by log2e so
// the per-edge exp is a bare v_exp_f32 (exp2).
__global__ void __launch_bounds__(256) k_edge_fused(
        const float* __restrict__ T, const void* __restrict__ attn, int l,
        const unsigned* __restrict__ gsrc, const unsigned* __restrict__ gdst,
        const int* __restrict__ rowptr, const uint4* __restrict__ emeta,
        float* __restrict__ h_att, const int* __restrict__ flagp) {
    const int f32 = *flagp;
    __shared__ f32x2 Ts2[38 * 64];          // [row][lane] = {head0, head1}
    const float* Tl = T + (size_t)l * NT_ROWS * HO;
    int tid = threadIdx.x;
    for (int i = tid; i < 38 * 64; i += 256) {
        int r = i >> 6, c = i & 63;
        Ts2[i] = (f32x2){Tl[r * HO + c], Tl[r * HO + 64 + c]};
    }
    int lane = tid & 63;
    f32x2 C2[6];
    #pragma unroll
    for (int r = 0; r < 6; r++)
        C2[r] = (f32x2){Tl[(38 + r) * HO + lane], Tl[(38 + r) * HO + 64 + lane]};
    const float LOG2E = 1.4426950408889634f;
    f32x2 AT2 = (f32x2){LD(attn, l * HO + lane, f32) * LOG2E,
                        LD(attn, l * HO + 64 + lane, f32) * LOG2E};
    __syncthreads();
    int wid = tid >> 6;
    int d0 = blockIdx.x * 8 + wid * 2;

    #pragma unroll 1
    for (int dn = 0; dn < 2; dn++) {
        int d = d0 + dn;
        int jb = __builtin_amdgcn_readfirstlane(rowptr[d]);
        int je = __builtin_amdgcn_readfirstlane(rowptr[d + 1]);
        // clamp target for padded fetches: valid for deg-0 nodes and end-of-array
        int last = je - 1;
        if (last < jb) last = jb;
        if (last > N_EDGES - 1) last = N_EDGES - 1;
        unsigned gd = gdst[(size_t)d * 64 + lane];
        f32x2 NJ2 = up2(gd) + C2[5];         // const row folded in
        f32x2 A2 = (f32x2){0.f, 0.f};
        float Lsp = 0.f;                     // split-space denominator

        // uniform (SGPR) edge-meta load
        auto fe = [&](int j_) -> uint4 {
            int jj = (j_ < last) ? j_ : last;
            jj = __builtin_amdgcn_readfirstlane(jj);
            return emeta[jj];
        };
        // per-lane gather from packed src buffer (address from SGPR em.w)
        auto fg = [&](const uint4& em) -> uint2 {
            return *(const uint2*)&gsrc[(size_t)(em.w >> 8) * 128 + lane * 2];
        };
        // -> s_out: head0 log2-logit sum lanes 0-31, head1 lanes 32-63
        auto logits = [&](const uint4& em, const uint2& g, float& s_out, f32x2& h2) {
            int et = (int)(em.w & 7u), ri = (int)((em.w >> 3) & 31u);
            f32x2 x = up2(g.x) + NJ2;
            x += Ts2[et * 64 + lane];
            x += Ts2[(7 + ri) * 64 + lane];
            x += plo(em.x) * C2[0];
            x += phi(em.x) * C2[1];
            x += plo(em.y) * C2[2];
            x += phi(em.y) * C2[3];
            x += plo(em.z) * C2[4];
            f32x2 xs = x * NEG_SLOPE;        // leaky = max(x, 0.2x) for slope<1
            x = __builtin_elementwise_max(x, xs);
            f32x2 p = x * AT2;               // log2-scaled
            h2 = up2(g.y);
            float pa = p.x, pb = p.y;
            pswap(pa, pb);                   // pa=[p0_lo|p1_lo], pb=[p0_hi|p1_hi]
            float s = pa + pb;               // lanes 0-31: head0, 32-63: head1
            s += __int_as_float(__builtin_amdgcn_update_dpp(0, __float_as_int(s), 0xB1, 0xF, 0xF, true));
            s += __int_as_float(__builtin_amdgcn_update_dpp(0, __float_as_int(s), 0x4E, 0xF, 0xF, true));
            s += __int_as_float(__builtin_amdgcn_update_dpp(0, __float_as_int(s), 0x141, 0xF, 0xF, true));
            s += __int_as_float(__builtin_amdgcn_update_dpp(0, __float_as_int(s), 0x140, 0xF, 0xF, true));
            s += __int_as_float(__builtin_amdgcn_ds_swizzle(__float_as_int(s), 0x401F));
            s_out = s;
        };
        auto upd = [&](float w, f32x2 h2) {  // takes pre-masked weight
            Lsp += w;
            float wa = w, wb = w;
            pswap(wa, wb);                   // wa = w0 all lanes, wb = w1 all lanes
            A2 += (f32x2){wa, wb} * h2;
        };

        // ---- software pipeline: em 2 groups ahead, g 1 group ahead ----
        uint4 eA0 = fe(jb),     eA1 = fe(jb + 1), eA2 = fe(jb + 2), eA3 = fe(jb + 3);
        uint4 eB0 = fe(jb + 4), eB1 = fe(jb + 5), eB2 = fe(jb + 6), eB3 = fe(jb + 7);
        uint2 gA0 = fg(eA0), gA1 = fg(eA1), gA2 = fg(eA2), gA3 = fg(eA3);
        int j = jb;
        #pragma unroll 1
        while (j < je) {
            // phase 1: process group j; prefetch em[j+8], g[j+4]
            uint4 eC0 = fe(j + 8), eC1 = fe(j + 9), eC2 = fe(j + 10), eC3 = fe(j + 11);
            uint2 gB0 = fg(eB0), gB1 = fg(eB1), gB2 = fg(eB2), gB3 = fg(eB3);
            {
                float s0, s1, s2, s3;
                f32x2 h0, h1, h2v, h3;
                logits(eA0, gA0, s0, h0);
                logits(eA1, gA1, s1, h1);
                logits(eA2, gA2, s2, h2v);
                logits(eA3, gA3, s3, h3);
                float w0 = __builtin_exp2f(s0);                       // j < je
                float w1 = (j + 1 < je) ? __builtin_exp2f(s1) : 0.f;  // uniform masks
                float w2 = (j + 2 < je) ? __builtin_exp2f(s2) : 0.f;
                float w3 = (j + 3 < je) ? __builtin_exp2f(s3) : 0.f;
                upd(w0, h0); upd(w1, h1); upd(w2, h2v); upd(w3, h3);
            }
            if (j + 4 >= je) break;
            // phase 2: process group j+4; prefetch em[j+12], g[j+8]
            uint4 eD0 = fe(j + 12), eD1 = fe(j + 13), eD2 = fe(j + 14), eD3 = fe(j + 15);
            uint2 gN0 = fg(eC0), gN1 = fg(eC1), gN2 = fg(eC2), gN3 = fg(eC3);
            {
                float s0, s1, s2, s3;
                f32x2 h0, h1, h2v, h3;
                logits(eB0, gB0, s0, h0);
                logits(eB1, gB1, s1, h1);
                logits(eB2, gB2, s2, h2v);
                logits(eB3, gB3, s3, h3);
                float w0 = __builtin_exp2f(s0);                       // j+4 < je
                float w1 = (j + 5 < je) ? __builtin_exp2f(s1) : 0.f;
                float w2 = (j + 6 < je) ? __builtin_exp2f(s2) : 0.f;
                float w3 = (j + 7 < je) ? __builtin_exp2f(s3) : 0.f;
                upd(w0, h0); upd(w1, h1); upd(w2, h2v); upd(w3, h3);
            }
            // rotate banks (SSA renames across the back-edge)
            eA0 = eC0; eA1 = eC1; eA2 = eC2; eA3 = eC3;
            eB0 = eD0; eB1 = eD1; eB2 = eD2; eB3 = eD3;
            gA0 = gN0; gA1 = gN1; gA2 = gN2; gA3 = gN3;
            j += 8;
        }

        float la = Lsp, lb = Lsp;
        pswap(la, lb);                       // la = L0 all lanes, lb = L1 all lanes
        h_att[(size_t)d * HO + lane]      = A2.x / (la + 1e-9f);
        h_att[(size_t)d * HO + 64 + lane] = A2.y / (lb + 1e-9f);
    }
}

// ---------------- node MLP + residual via MFMA ------------------------------
__global__ void __launch_bounds__(256) k_mlp(
        const float* __restrict__ h_att,
        const unsigned short* __restrict__ pw_m0, const void* __restrict__ bm0,
        const unsigned short* __restrict__ pw_m1, const void* __restrict__ bm1, int l,
        float* __restrict__ feats, int prev_off, int out_off,
        const int* __restrict__ flagp) {
    const int f32 = *flagp;
    __shared__ __align__(16) unsigned short Xs[64 * 136];
    __shared__ __align__(16) unsigned short W0T[128 * 136];
    __shared__ __align__(16) unsigned short W1T[64 * 136];
    __shared__ float sb0[HO], sb1[64];
    int tid = threadIdx.x, n0 = blockIdx.x * 64;
    for (int i = tid; i < 64 * 128; i += 256) {
        int n = i >> 7, c = i & 127, gn = n0 + n;
        Xs[n * 136 + c] = rnebf((gn < N_NODES) ? h_att[(size_t)gn * HO + c] : 0.f);
    }
    const uint4* p0 = (const uint4*)pw_m0 + (size_t)l * 2048;
    for (int i = tid; i < 2048; i += 256) {   // i = c*16 + kq
        int kq = i & 15, c = i >> 4;
        *(uint4*)&W0T[c * 136 + kq * 8] = p0[i];
    }
    const uint4* p1 = (const uint4*)pw_m1 + (size_t)l * 1024;
    for (int i = tid; i < 1024; i += 256) {
        int kq = i & 15, c = i >> 4;
        *(uint4*)&W1T[c * 136 + kq * 8] = p1[i];
    }
    for (int i = tid; i < HO; i += 256) sb0[i] = LD(bm0, l * HO + i, f32);
    for (int i = tid; i < 64; i += 256) sb1[i] = LD(bm1, l * 64 + i, f32);
    __syncthreads();
    int wid = tid >> 6, lane = tid & 63;
    int row0 = wid * 16, mrow = lane & 15, quad = lane >> 4;
    f32x4 acc[8];
    #pragma unroll
    for (int j = 0; j < 8; j++) {
        float b = sb0[j * 16 + mrow];
        acc[j] = (f32x4){b, b, b, b};
    }
    #pragma unroll
    for (int ks = 0; ks < 4; ks++) {
        bf16x8 a = *(const bf16x8*)&Xs[(row0 + mrow) * 136 + ks * 32 + quad * 8];
        #pragma unroll
        for (int j = 0; j < 8; j++) {
            bf16x8 b = *(const bf16x8*)&W0T[(j * 16 + mrow) * 136 + ks * 32 + quad * 8];
            acc[j] = __builtin_amdgcn_mfma_f32_16x16x32_bf16(a, b, acc[j], 0, 0, 0);
        }
    }
    #pragma unroll
    for (int j = 0; j < 8; j++)
        #pragma unroll
        for (int r = 0; r < 4; r++)
            Xs[(row0 + quad * 4 + r) * 136 + j * 16 + mrow] = rnebf(fmaxf(acc[j][r], 0.f));
    f32x4 o[4];
    #pragma unroll
    for (int j = 0; j < 4; j++) {
        float b = sb1[j * 16 + mrow];
        o[j] = (f32x4){b, b, b, b};
    }
    #pragma unroll
    for (int ks = 0; ks < 4; ks++) {
        bf16x8 a = *(const bf16x8*)&Xs[(row0 + mrow) * 136 + ks * 32 + quad * 8];
        #pragma unroll
        for (int j = 0; j < 4; j++) {
            bf16x8 b = *(const bf16x8*)&W1T[(j * 16 + mrow) * 136 + ks * 32 + quad * 8];
            o[j] = __builtin_amdgcn_mfma_f32_16x16x32_bf16(a, b, o[j], 0, 0, 0);
        }
    }
    #pragma unroll
    for (int j = 0; j < 4; j++) {
        int c = j * 16 + mrow;
        #pragma unroll
        for (int r = 0; r < 4; r++) {
            int gn = n0 + row0 + quad * 4 + r;
            if (gn < N_NODES) {
                float* rw = feats + (size_t)gn * F_TOT;
                rw[out_off + c] = o[j][r] + rw[prev_off + c];
            }
        }
    }
}

// ---------------- graph max pool -------------------------------------------
__global__ void k_pool(const float* __restrict__ feats, unsigned* __restrict__ gmax) {
    int g = blockIdx.x;
    int chunk = blockIdx.y;
    int t = threadIdx.x;
    const int CS = 49;
    int nb = chunk * CS;
    int ne = (nb + CS < NPG) ? nb + CS : NPG;
    float m0 = -INFINITY, m1 = -INFINITY;
    for (int n = nb; n < ne; n++) {
        const float* row = feats + (size_t)(g * NPG + n) * F_TOT;
        m0 = fmaxf(m0, row[t]);
        if (t + 256 < F_TOT) m1 = fmaxf(m1, row[t + 256]);
    }
    atomicMax(&gmax[g * F_TOT + t], fkey(m0));
    if (t + 256 < F_TOT) atomicMax(&gmax[g * F_TOT + t + 256], fkey(m1));
}

// ---------------- output write: wave per row --------------------------------
__global__ void k_out(const float* __restrict__ feats, const unsigned* __restrict__ gmax,
                      void* __restrict__ out, const int* __restrict__ flagp) {
    const int f32 = *flagp;
    int lane = threadIdx.x & 63;
    int wave = (blockIdx.x * blockDim.x + threadIdx.x) >> 6;
    int nw = (gridDim.x * blockDim.x) >> 6;
    for (int row = wave; row < B_GRAPHS * NPG; row += nw) {
        int g = row / NPG;
        const float* fr = feats + (size_t)row * F_TOT;
        const unsigned* gr = gmax + g * F_TOT;
        if (f32) {
            float* o = (float*)out + (size_t)row * OUT_C;
            for (int c = lane; c < OUT_C; c += 64)
                o[c] = (c < F_TOT) ? fr[c] : funkey(gr[c - F_TOT]);
        } else {
            __hip_bfloat16* o = (__hip_bfloat16*)out + (size_t)row * OUT_C;
            for (int c = lane; c < OUT_C; c += 64)
                o[c] = __float2bfloat16((c < F_TOT) ? fr[c] : funkey(gr[c - F_TOT]));
        }
    }
}

extern "C" void kernel_launch(void* const* d_in, const int* in_sizes, int n_in,
                              void* d_out, int out_size, void* d_ws, size_t ws_size,
                              hipStream_t stream) {
    const void* feat      = d_in[0];
    const void* att_rc    = d_in[1];
    const void* att_rp    = d_in[2];
    const void* etype_emb = d_in[3];
    const void* rid_emb   = d_in[4];
    const void* rc_W      = d_in[5];
    const void* rc_b      = d_in[6];
    const void* rp_W      = d_in[7];
    const void* rp_b      = d_in[8];
    const void* fe_W0     = d_in[9];
    const void* fe_b0     = d_in[10];
    const void* fe_W1     = d_in[11];
    const void* fe_b1     = d_in[12];
    const void* W_ni      = d_in[13];
    const void* W_nj      = d_in[14];
    const void* W_fij     = d_in[15];
    const void* W_node    = d_in[16];
    const void* attn      = d_in[17];
    const void* egat_bias = d_in[18];
    const void* Wm0       = d_in[19];
    const void* bm0       = d_in[20];
    const void* Wm1       = d_in[21];
    const void* bm1       = d_in[22];
    const int* src   = (const int*)d_in[23];
    const int* dst   = (const int*)d_in[24];
    const int* etype = (const int*)d_in[25];
    const int* rid   = (const int*)d_in[26];

    char* p = (char*)d_ws;
    auto alloc = [&](size_t bytes) {
        char* r = p;
        p += (bytes + 255) & ~(size_t)255;
        return r;
    };
    float*    feats  = (float*)alloc((size_t)N_NODES * F_TOT * 4);
    unsigned* gsrc   = (unsigned*)alloc((size_t)N_NODES * HO * 4);
    unsigned* gdst   = (unsigned*)alloc((size_t)N_NODES * 64 * 4);
    float*    h_att  = (float*)alloc((size_t)N_NODES * HO * 4);
    float*    T      = (float*)alloc((size_t)3 * NT_ROWS * HO * 4);
    unsigned* gmax   = (unsigned*)alloc((size_t)B_GRAPHS * F_TOT * 4);
    int*      flagp  = (int*)alloc(256);
    int*      rowptr = (int*)alloc((size_t)(N_NODES + 1) * 4);
    int*      cursor = (int*)alloc((size_t)N_NODES * 4);
    int*      cnt    = (int*)alloc((size_t)N_NODES * 4);
    int*      bsum   = (int*)alloc((size_t)SCB * 4);
    int*      boff   = (int*)alloc((size_t)SCB * 4);
    uint4*    emeta  = (uint4*)alloc((size_t)N_EDGES * 16);
    unsigned short* pw_n  = (unsigned short*)alloc((size_t)73728 * 2);
    unsigned short* pw_m0 = (unsigned short*)alloc((size_t)49152 * 2);
    unsigned short* pw_m1 = (unsigned short*)alloc((size_t)24576 * 2);

    k_detect<<<1, 256, 0, stream>>>(att_rc, flagp);
    hipMemsetAsync(cnt, 0, (size_t)N_NODES * 4, stream);
    hipMemsetAsync(gmax, 0, (size_t)B_GRAPHS * F_TOT * 4, stream);
    k_wprep<<<576, 256, 0, stream>>>(W_ni, W_nj, W_node, Wm0, Wm1,
                                     pw_n, pw_m0, pw_m1, flagp);
    k_count<<<512, 256, 0, stream>>>(dst, cnt);
    k_scan1<<<SCB, 256, 0, stream>>>(cnt, bsum);
    k_scan2<<<1, 256, 0, stream>>>(bsum, boff);
    k_scan3<<<SCB, 256, 0, stream>>>(cnt, boff, rowptr, cursor);
    k_fill<<<1024, 256, 0, stream>>>(src, dst, etype, rid, att_rc, att_rp,
                                     cursor, emeta, flagp);
    k_init<<<(N_NODES + 63) / 64, 256, 0, stream>>>(feat, fe_W0, fe_b0, fe_W1, fe_b1,
                                                    feats, flagp);
    k_tables<<<3, 256, 0, stream>>>(etype_emb, rid_emb, rc_W, rc_b, rp_W, rp_b,
                                    W_fij, egat_bias, T, flagp);
    for (int l = 0; l < 3; l++) {
        int h_off = IN_DIM + l * HID;
        int out_off = IN_DIM + (l + 1) * HID;
        k_ngemm<<<(N_NODES + 63) / 64, 256, 0, stream>>>(feats, h_off, pw_n, l, gsrc, gdst);
        k_edge_fused<<<N_NODES / 8, 256, 0, stream>>>(T, attn, l, gsrc, gdst,
                                                      rowptr, emeta, h_att, flagp);
        k_mlp<<<(N_NODES + 63) / 64, 256, 0, stream>>>(h_att, pw_m0, bm0, pw_m1, bm1, l,
                                                       feats, h_off, out_off, flagp);
    }
    k_pool<<<dim3(B_GRAPHS, 128), 256, 0, stream>>>(feats, gmax);
    k_out<<<2048, 256, 0, stream>>>(feats, gmax, d_out, flagp);
}

// Round 7
// 677.318 us; speedup vs baseline: 1.2396x; 1.0632x over previous
//
#include <hip/hip_runtime.h>
#include <hip/hip_bf16.h>
#include <math.h>

#define N_NODES 50000
#define N_EDGES 500000
#define B_GRAPHS 8
#define NPG 6250
#define HID 64
#define HO 128          // HEADS*HID
#define IN_DIM 10
#define F_TOT 266       // IN_DIM + 4*HID
#define OUT_C 532       // 2*F_TOT
#define NEG_SLOPE 0.2f
#define NT_ROWS 44      // 7 etype + 31 rid + 2 rc + 3 rp + 1 const
#define SCB 200         // scan blocks
#define SCH 250         // scan chunk (SCB*SCH == N_NODES)

typedef short bf16x8 __attribute__((ext_vector_type(8)));
typedef float f32x4 __attribute__((ext_vector_type(4)));
typedef float f32x2 __attribute__((ext_vector_type(2)));
typedef unsigned u32x2v __attribute__((ext_vector_type(2)));

// dtype-agnostic float load: f32 flag chooses fp32 or bf16 interpretation
__device__ __forceinline__ float LD(const void* p, size_t i, int f32) {
    if (f32) return ((const float*)p)[i];
    unsigned u = ((const unsigned short*)p)[i];
    return __uint_as_float(u << 16);
}
__device__ __forceinline__ unsigned fkey(float f) {
    unsigned b = __float_as_uint(f);
    return (b & 0x80000000u) ? ~b : (b | 0x80000000u);
}
__device__ __forceinline__ float funkey(unsigned k) {
    unsigned b = (k & 0x80000000u) ? (k & 0x7fffffffu) : ~k;
    return __uint_as_float(b);
}
__device__ __forceinline__ unsigned short rnebf(float x) {
    unsigned u = __float_as_uint(x);
    return (unsigned short)((u + 0x7FFFu + ((u >> 16) & 1u)) >> 16);
}
__device__ __forceinline__ unsigned pk2(float lo, float hi) {
    return (unsigned)rnebf(lo) | ((unsigned)rnebf(hi) << 16);
}
__device__ __forceinline__ float plo(unsigned u) { return __uint_as_float(u << 16); }
__device__ __forceinline__ float phi(unsigned u) { return __uint_as_float(u & 0xFFFF0000u); }
// unpack a (lo,hi) bf16 pair to float2
__device__ __forceinline__ f32x2 up2(unsigned u) {
    return (f32x2){__uint_as_float(u << 16), __uint_as_float(u & 0xFFFF0000u)};
}
// half-wave swap via the backend-modeled intrinsic (NOT inline asm: two "+v"
// asm operands fed the same value can be register-coalesced into ONE VGPR,
// turning the swap into v_permlane32_swap v5,v5 — the round-2 correctness bug).
// after pswap(a,b): a = [a_lo|b_lo], b = [a_hi|b_hi]
__device__ __forceinline__ void pswap(float& a, float& b) {
    u32x2v r = __builtin_amdgcn_permlane32_swap(__float_as_uint(a), __float_as_uint(b),
                                                false, false);
    a = __uint_as_float(r.x);
    b = __uint_as_float(r.y);
}

// ---------------- dtype detection ------------------------------------------
__global__ void k_detect(const void* __restrict__ att_rc, int* __restrict__ flagp) {
    __shared__ int cnt;
    if (threadIdx.x == 0) cnt = 0;
    __syncthreads();
    const unsigned short* w = (const unsigned short*)att_rc;
    int c = 0;
    for (int i = threadIdx.x; i < 8192; i += 256) {
        unsigned e = (w[i] >> 7) & 0xFF;
        if (e >= 0xC0) c++;
    }
    atomicAdd(&cnt, c);
    __syncthreads();
    if (threadIdx.x == 0) *flagp = (cnt > 8) ? 1 : 0;
}

// ---------------- weight pre-pack + zeroing + edge tables (fused) ----------
// blocks 0..575   : weight pre-pack to bf16 (transposed layouts)
// blocks 576..779 : zero cnt[50000] and gmax[2128]  (replaces 2 memsets)
// blocks 780..782 : edge-table precompute (was k_tables), l = b - 780
// GRID MUST BE 783. Round-6 bug: grid 784 sent b=783 into the tables branch
// with l=3 -> OOB write past T that corrupted gmax AND flagp (dtype flag).
__global__ void k_wprep(const void* __restrict__ W_ni, const void* __restrict__ W_nj,
                        const void* __restrict__ W_node, const void* __restrict__ Wm0,
                        const void* __restrict__ Wm1,
                        unsigned short* __restrict__ pw_n,
                        unsigned short* __restrict__ pw_m0,
                        unsigned short* __restrict__ pw_m1,
                        const int* __restrict__ flagp,
                        const void* __restrict__ etype_emb, const void* __restrict__ rid_emb,
                        const void* __restrict__ rc_W, const void* __restrict__ rc_b,
                        const void* __restrict__ rp_W, const void* __restrict__ rp_b,
                        const void* __restrict__ W_fij, const void* __restrict__ egat_bias,
                        float* __restrict__ T,
                        int* __restrict__ cnt, unsigned* __restrict__ gmax) {
    __shared__ float S[NT_ROWS * HID];
    __shared__ float W[HID * HO];
    const int f32 = *flagp;
    int b = blockIdx.x;
    if (b < 576) {
        int i = b * 256 + threadIdx.x;
        if (i < 73728) {                      // 3l x 3m x 128c x 64k
            int k = i & 63, c = (i >> 6) & 127, lm = i >> 13;
            int m = lm % 3, l = lm / 3;
            const void* Wp = (m == 0) ? W_ni : (m == 1) ? W_nj : W_node;
            pw_n[i] = rnebf(LD(Wp, (size_t)l * 8192 + k * 128 + c, f32));
        } else if (i < 73728 + 49152) {       // 3l x 128c x 128k
            int j = i - 73728;
            int k = j & 127, c = (j >> 7) & 127, l = j >> 14;
            pw_m0[j] = rnebf(LD(Wm0, (size_t)l * 16384 + k * 128 + c, f32));
        } else if (i < 147456) {              // 3l x 64c x 128k
            int j = i - 122880;
            int k = j & 127, c = (j >> 7) & 63, l = j >> 13;
            pw_m1[j] = rnebf(LD(Wm1, (size_t)l * 8192 + k * 64 + c, f32));
        }
    } else if (b < 780) {
        int i2 = (b - 576) * 256 + threadIdx.x;
        if (i2 < N_NODES) cnt[i2] = 0;
        else {
            int g = i2 - N_NODES;
            if (g < B_GRAPHS * F_TOT) gmax[g] = 0;
        }
    } else {
        int l = b - 780;
        if (l < 3) {                          // guard the grid-range arithmetic
            for (int i = threadIdx.x; i < 7 * HID; i += 256) S[i] = LD(etype_emb, i, f32);
            for (int i = threadIdx.x; i < 31 * HID; i += 256) S[7 * HID + i] = LD(rid_emb, i, f32);
            for (int i = threadIdx.x; i < 2 * HID; i += 256) S[38 * HID + i] = LD(rc_W, i, f32);
            for (int i = threadIdx.x; i < 3 * HID; i += 256) S[40 * HID + i] = LD(rp_W, i, f32);
            for (int i = threadIdx.x; i < HID; i += 256)
                S[43 * HID + i] = LD(rc_b, i, f32) + LD(rp_b, i, f32);
            for (int i = threadIdx.x; i < HID * HO; i += 256)
                W[i] = LD(W_fij, (size_t)l * HID * HO + i, f32);
            __syncthreads();
            for (int idx = threadIdx.x; idx < NT_ROWS * HO; idx += 256) {
                int r = idx / HO, c = idx % HO;
                float acc = (r == 43) ? LD(egat_bias, l * HO + c, f32) : 0.f;
                for (int k = 0; k < HID; k++) acc += S[r * HID + k] * W[k * HO + c];
                T[(size_t)l * NT_ROWS * HO + idx] = acc;
            }
        }
    }
}

// ---------------- CSR build ------------------------------------------------
__global__ void k_count(const int* __restrict__ dst, int* __restrict__ cnt) {
    int i = blockIdx.x * blockDim.x + threadIdx.x;
    int stride = gridDim.x * blockDim.x;
    for (int e = i; e < N_EDGES; e += stride) atomicAdd(&cnt[dst[e]], 1);
}

__global__ void k_scan1(const int* __restrict__ cnt, int* __restrict__ bsum) {
    __shared__ int red[256];
    int b = blockIdx.x, t = threadIdx.x;
    red[t] = (t < SCH) ? cnt[b * SCH + t] : 0;
    __syncthreads();
    for (int off = 128; off; off >>= 1) {
        if (t < off) red[t] += red[t + off];
        __syncthreads();
    }
    if (t == 0) bsum[b] = red[0];
}
// scan3 computes its own block offset from bsum (scan2 eliminated):
// each block tree-reduces bsum[0..b) — 200 ints, trivial redundant work.
__global__ void k_scan3(const int* __restrict__ cnt, const int* __restrict__ bsum,
                        int* __restrict__ rowptr, int* __restrict__ cursor) {
    __shared__ int red[256];
    __shared__ int ts[256];
    int b = blockIdx.x, t = threadIdx.x;
    red[t] = (t < b && t < SCB) ? bsum[t] : 0;
    __syncthreads();
    for (int off = 128; off; off >>= 1) {
        if (t < off) red[t] += red[t + off];
        __syncthreads();
    }
    int boff_b = red[0];        // exclusive prefix over blocks (valid after syncs)
    __syncthreads();
    int base = b * SCH;
    int v = (t < SCH) ? cnt[base + t] : 0;
    ts[t] = v;
    __syncthreads();
    for (int off = 1; off < 256; off <<= 1) {
        int u = (t >= off) ? ts[t - off] : 0;
        __syncthreads();
        ts[t] += u;
        __syncthreads();
    }
    if (t < SCH) {
        int r = boff_b + ts[t] - v;
        rowptr[base + t] = r;
        cursor[base + t] = r;
    }
    if (b == SCB - 1 && t == SCH - 1) rowptr[N_NODES] = boff_b + ts[t];
}

// emeta.w = etype | rid<<3 | src<<8   (src < 65536)
__global__ void k_fill(const int* __restrict__ src, const int* __restrict__ dst,
                       const int* __restrict__ etype, const int* __restrict__ rid,
                       const void* __restrict__ att_rc, const void* __restrict__ att_rp,
                       int* __restrict__ cursor, uint4* __restrict__ emeta,
                       const int* __restrict__ flagp) {
    const int f32 = *flagp;
    int i = blockIdx.x * blockDim.x + threadIdx.x;
    int stride = gridDim.x * blockDim.x;
    for (int e = i; e < N_EDGES; e += stride) {
        int d = dst[e];
        int j = atomicAdd(&cursor[d], 1);
        float rc0 = LD(att_rc, 2 * (size_t)e, f32), rc1 = LD(att_rc, 2 * (size_t)e + 1, f32);
        float rp0 = LD(att_rp, 3 * (size_t)e, f32), rp1 = LD(att_rp, 3 * (size_t)e + 1, f32),
              rp2 = LD(att_rp, 3 * (size_t)e + 2, f32);
        uint4 m;
        m.x = pk2(rc0, rc1);
        m.y = pk2(rp0, rp1);
        m.z = pk2(rp2, 0.f);
        m.w = (unsigned)(etype[e] | (rid[e] << 3) | ((unsigned)src[e] << 8));
        emeta[j] = m;
    }
}

// ---------------- initial feature MLP --------------------------------------
__global__ void k_init(const void* __restrict__ feat,
                       const void* __restrict__ W0, const void* __restrict__ b0,
                       const void* __restrict__ W1, const void* __restrict__ b1,
                       float* __restrict__ feats, const int* __restrict__ flagp) {
    const int f32 = *flagp;
    __shared__ float sf[64 * 12];
    __shared__ float sW0[IN_DIM * 64];
    __shared__ float sb0[64], sb1[64];
    __shared__ float sh[64 * 64];
    __shared__ float sW1[64 * 64];
    int tid = threadIdx.x, n0 = blockIdx.x * 64;
    for (int i = tid; i < IN_DIM * 64; i += 256) sW0[i] = LD(W0, i, f32);
    for (int i = tid; i < 64; i += 256) { sb0[i] = LD(b0, i, f32); sb1[i] = LD(b1, i, f32); }
    for (int i = tid; i < 64 * 64; i += 256) sW1[i] = LD(W1, i, f32);
    for (int i = tid; i < 64 * IN_DIM; i += 256) {
        int n = n0 + i / IN_DIM, c = i % IN_DIM;
        sf[(i / IN_DIM) * 12 + c] = (n < N_NODES) ? LD(feat, (size_t)n * IN_DIM + c, f32) : 0.f;
    }
    __syncthreads();
    int ng = tid / 16, cg = tid % 16;
    float acc[4][4];
    #pragma unroll
    for (int i = 0; i < 4; i++)
        #pragma unroll
        for (int j = 0; j < 4; j++) acc[i][j] = sb0[cg * 4 + j];
    #pragma unroll
    for (int k = 0; k < IN_DIM; k++)
        #pragma unroll
        for (int i = 0; i < 4; i++) {
            float a = sf[(ng * 4 + i) * 12 + k];
            #pragma unroll
            for (int j = 0; j < 4; j++) acc[i][j] += a * sW0[k * 64 + cg * 4 + j];
        }
    #pragma unroll
    for (int i = 0; i < 4; i++)
        #pragma unroll
        for (int j = 0; j < 4; j++) sh[(ng * 4 + i) * 64 + cg * 4 + j] = fmaxf(acc[i][j], 0.f);
    __syncthreads();
    float o[4][4];
    #pragma unroll
    for (int i = 0; i < 4; i++)
        #pragma unroll
        for (int j = 0; j < 4; j++) o[i][j] = sb1[cg * 4 + j];
    for (int k = 0; k < 64; k++) {
        float4 bv = *(const float4*)&sW1[k * 64 + cg * 4];
        #pragma unroll
        for (int i = 0; i < 4; i++) {
            float a = sh[(ng * 4 + i) * 64 + k];
            o[i][0] += a * bv.x; o[i][1] += a * bv.y;
            o[i][2] += a * bv.z; o[i][3] += a * bv.w;
        }
    }
    #pragma unroll
    for (int i = 0; i < 4; i++) {
        int n = n0 + ng * 4 + i;
        if (n < N_NODES) {
            float* r = feats + (size_t)n * F_TOT;
            #pragma unroll
            for (int j = 0; j < 4; j++) r[IN_DIM + cg * 4 + j] = o[i][j];
        }
    }
    for (int i = tid; i < 64 * IN_DIM; i += 256) {
        int n = n0 + i / IN_DIM, c = i % IN_DIM;
        if (n < N_NODES) feats[(size_t)n * F_TOT + c] = sf[(i / IN_DIM) * 12 + c];
    }
}

// ---------------- node GEMMs via MFMA -> packed bf16 gather buffers --------
// (standalone: layer 0 only; layers 1,2 are produced inside fused k_mlp)
__global__ void __launch_bounds__(256) k_ngemm(
        const float* __restrict__ feats, int h_off,
        const unsigned short* __restrict__ pw_n, int l,
        unsigned* __restrict__ gsrc, unsigned* __restrict__ gdst) {
    __shared__ __align__(16) unsigned short Xs[64 * 72];
    __shared__ __align__(16) unsigned short Ws[384 * 72];
    int tid = threadIdx.x, n0 = blockIdx.x * 64;
    for (int i = tid; i < 64 * 64; i += 256) {
        int n = i >> 6, c = i & 63, gn = n0 + n;
        Xs[n * 72 + c] = rnebf((gn < N_NODES) ? feats[(size_t)gn * F_TOT + h_off + c] : 0.f);
    }
    const uint4* pn = (const uint4*)pw_n + (size_t)l * 3072;
    for (int i = tid; i < 3072; i += 256) {   // i = (m*128+c)*8 + kq
        int kq = i & 7, mc = i >> 3;
        *(uint4*)&Ws[mc * 72 + kq * 8] = pn[i];
    }
    __syncthreads();
    int wid = tid >> 6, lane = tid & 63;
    int row0 = wid * 16, mrow = lane & 15, quad = lane >> 4;
    bf16x8 a0 = *(const bf16x8*)&Xs[(row0 + mrow) * 72 + quad * 8];
    bf16x8 a1 = *(const bf16x8*)&Xs[(row0 + mrow) * 72 + 32 + quad * 8];
    f32x4 accA[8], accB[8];
    #pragma unroll
    for (int j = 0; j < 8; j++) { accA[j] = (f32x4){0,0,0,0}; accB[j] = (f32x4){0,0,0,0}; }
    #pragma unroll
    for (int j = 0; j < 8; j++) {
        bf16x8 b0 = *(const bf16x8*)&Ws[(0 * 128 + j * 16 + mrow) * 72 + quad * 8];
        bf16x8 b1 = *(const bf16x8*)&Ws[(0 * 128 + j * 16 + mrow) * 72 + 32 + quad * 8];
        accA[j] = __builtin_amdgcn_mfma_f32_16x16x32_bf16(a0, b0, accA[j], 0, 0, 0);
        accA[j] = __builtin_amdgcn_mfma_f32_16x16x32_bf16(a1, b1, accA[j], 0, 0, 0);
        bf16x8 c0 = *(const bf16x8*)&Ws[(2 * 128 + j * 16 + mrow) * 72 + quad * 8];
        bf16x8 c1 = *(const bf16x8*)&Ws[(2 * 128 + j * 16 + mrow) * 72 + 32 + quad * 8];
        accB[j] = __builtin_amdgcn_mfma_f32_16x16x32_bf16(a0, c0, accB[j], 0, 0, 0);
        accB[j] = __builtin_amdgcn_mfma_f32_16x16x32_bf16(a1, c1, accB[j], 0, 0, 0);
    }
    #pragma unroll
    for (int j = 0; j < 4; j++) {
        int c = j * 16 + mrow;
        #pragma unroll
        for (int r = 0; r < 4; r++) {
            int gn = n0 + row0 + quad * 4 + r;
            if (gn < N_NODES) {
                uint2 v;
                v.x = pk2(accA[j][r], accA[j + 4][r]);
                v.y = pk2(accB[j][r], accB[j + 4][r]);
                *(uint2*)&gsrc[(size_t)gn * 128 + c * 2] = v;
            }
        }
    }
    f32x4 accC[8];
    #pragma unroll
    for (int j = 0; j < 8; j++) accC[j] = (f32x4){0,0,0,0};
    #pragma unroll
    for (int j = 0; j < 8; j++) {
        bf16x8 b0 = *(const bf16x8*)&Ws[(1 * 128 + j * 16 + mrow) * 72 + quad * 8];
        bf16x8 b1 = *(const bf16x8*)&Ws[(1 * 128 + j * 16 + mrow) * 72 + 32 + quad * 8];
        accC[j] = __builtin_amdgcn_mfma_f32_16x16x32_bf16(a0, b0, accC[j], 0, 0, 0);
        accC[j] = __builtin_amdgcn_mfma_f32_16x16x32_bf16(a1, b1, accC[j], 0, 0, 0);
    }
    #pragma unroll
    for (int j = 0; j < 4; j++) {
        int c = j * 16 + mrow;
        #pragma unroll
        for (int r = 0; r < 4; r++) {
            int gn = n0 + row0 + quad * 4 + r;
            if (gn < N_NODES)
                gdst[(size_t)gn * 64 + c] = pk2(accC[j][r], accC[j + 4][r]);
        }
    }
}

// ---------------- fused edge phase (round-5 verified version) ---------------
__global__ void __launch_bounds__(256) k_edge_fused(
        const float* __restrict__ T, const void* __restrict__ attn, int l,
        const unsigned* __restrict__ gsrc, const unsigned* __restrict__ gdst,
        const int* __restrict__ rowptr, const uint4* __restrict__ emeta,
        float* __restrict__ h_att, const int* __restrict__ flagp) {
    const int f32 = *flagp;
    __shared__ f32x2 Ts2[38 * 64];          // [row][lane] = {head0, head1}
    const float* Tl = T + (size_t)l * NT_ROWS * HO;
    int tid = threadIdx.x;
    for (int i = tid; i < 38 * 64; i += 256) {
        int r = i >> 6, c = i & 63;
        Ts2[i] = (f32x2){Tl[r * HO + c], Tl[r * HO + 64 + c]};
    }
    int lane = tid & 63;
    f32x2 C2[6];
    #pragma unroll
    for (int r = 0; r < 6; r++)
        C2[r] = (f32x2){Tl[(38 + r) * HO + lane], Tl[(38 + r) * HO + 64 + lane]};
    const float LOG2E = 1.4426950408889634f;
    f32x2 AT2 = (f32x2){LD(attn, l * HO + lane, f32) * LOG2E,
                        LD(attn, l * HO + 64 + lane, f32) * LOG2E};
    __syncthreads();
    int wid = tid >> 6;
    int d0 = blockIdx.x * 8 + wid * 2;

    #pragma unroll 1
    for (int dn = 0; dn < 2; dn++) {
        int d = d0 + dn;
        int jb = __builtin_amdgcn_readfirstlane(rowptr[d]);
        int je = __builtin_amdgcn_readfirstlane(rowptr[d + 1]);
        int last = je - 1;
        if (last < jb) last = jb;
        if (last > N_EDGES - 1) last = N_EDGES - 1;
        unsigned gd = gdst[(size_t)d * 64 + lane];
        f32x2 NJ2 = up2(gd) + C2[5];         // const row folded in
        f32x2 A2 = (f32x2){0.f, 0.f};
        float Lsp = 0.f;                     // split-space denominator

        auto fe = [&](int j_) -> uint4 {
            int jj = (j_ < last) ? j_ : last;
            jj = __builtin_amdgcn_readfirstlane(jj);
            return emeta[jj];
        };
        auto fg = [&](const uint4& em) -> uint2 {
            return *(const uint2*)&gsrc[(size_t)(em.w >> 8) * 128 + lane * 2];
        };
        auto logits = [&](const uint4& em, const uint2& g, float& s_out, f32x2& h2) {
            int et = (int)(em.w & 7u), ri = (int)((em.w >> 3) & 31u);
            f32x2 x = up2(g.x) + NJ2;
            x += Ts2[et * 64 + lane];
            x += Ts2[(7 + ri) * 64 + lane];
            x += plo(em.x) * C2[0];
            x += phi(em.x) * C2[1];
            x += plo(em.y) * C2[2];
            x += phi(em.y) * C2[3];
            x += plo(em.z) * C2[4];
            f32x2 xs = x * NEG_SLOPE;        // leaky = max(x, 0.2x) for slope<1
            x = __builtin_elementwise_max(x, xs);
            f32x2 p = x * AT2;               // log2-scaled
            h2 = up2(g.y);
            float pa = p.x, pb = p.y;
            pswap(pa, pb);                   // pa=[p0_lo|p1_lo], pb=[p0_hi|p1_hi]
            float s = pa + pb;               // lanes 0-31: head0, 32-63: head1
            s += __int_as_float(__builtin_amdgcn_update_dpp(0, __float_as_int(s), 0xB1, 0xF, 0xF, true));
            s += __int_as_float(__builtin_amdgcn_update_dpp(0, __float_as_int(s), 0x4E, 0xF, 0xF, true));
            s += __int_as_float(__builtin_amdgcn_update_dpp(0, __float_as_int(s), 0x141, 0xF, 0xF, true));
            s += __int_as_float(__builtin_amdgcn_update_dpp(0, __float_as_int(s), 0x140, 0xF, 0xF, true));
            s += __int_as_float(__builtin_amdgcn_ds_swizzle(__float_as_int(s), 0x401F));
            s_out = s;
        };
        auto upd = [&](float w, f32x2 h2) {  // takes pre-masked weight
            Lsp += w;
            float wa = w, wb = w;
            pswap(wa, wb);                   // wa = w0 all lanes, wb = w1 all lanes
            A2 += (f32x2){wa, wb} * h2;
        };

        // ---- software pipeline: em 2 groups ahead, g 1 group ahead ----
        uint4 eA0 = fe(jb),     eA1 = fe(jb + 1), eA2 = fe(jb + 2), eA3 = fe(jb + 3);
        uint4 eB0 = fe(jb + 4), eB1 = fe(jb + 5), eB2 = fe(jb + 6), eB3 = fe(jb + 7);
        uint2 gA0 = fg(eA0), gA1 = fg(eA1), gA2 = fg(eA2), gA3 = fg(eA3);
        int j = jb;
        #pragma unroll 1
        while (j < je) {
            uint4 eC0 = fe(j + 8), eC1 = fe(j + 9), eC2 = fe(j + 10), eC3 = fe(j + 11);
            uint2 gB0 = fg(eB0), gB1 = fg(eB1), gB2 = fg(eB2), gB3 = fg(eB3);
            {
                float s0, s1, s2, s3;
                f32x2 h0, h1, h2v, h3;
                logits(eA0, gA0, s0, h0);
                logits(eA1, gA1, s1, h1);
                logits(eA2, gA2, s2, h2v);
                logits(eA3, gA3, s3, h3);
                float w0 = __builtin_exp2f(s0);
                float w1 = (j + 1 < je) ? __builtin_exp2f(s1) : 0.f;
                float w2 = (j + 2 < je) ? __builtin_exp2f(s2) : 0.f;
                float w3 = (j + 3 < je) ? __builtin_exp2f(s3) : 0.f;
                upd(w0, h0); upd(w1, h1); upd(w2, h2v); upd(w3, h3);
            }
            if (j + 4 >= je) break;
            uint4 eD0 = fe(j + 12), eD1 = fe(j + 13), eD2 = fe(j + 14), eD3 = fe(j + 15);
            uint2 gN0 = fg(eC0), gN1 = fg(eC1), gN2 = fg(eC2), gN3 = fg(eC3);
            {
                float s0, s1, s2, s3;
                f32x2 h0, h1, h2v, h3;
                logits(eB0, gB0, s0, h0);
                logits(eB1, gB1, s1, h1);
                logits(eB2, gB2, s2, h2v);
                logits(eB3, gB3, s3, h3);
                float w0 = __builtin_exp2f(s0);
                float w1 = (j + 5 < je) ? __builtin_exp2f(s1) : 0.f;
                float w2 = (j + 6 < je) ? __builtin_exp2f(s2) : 0.f;
                float w3 = (j + 7 < je) ? __builtin_exp2f(s3) : 0.f;
                upd(w0, h0); upd(w1, h1); upd(w2, h2v); upd(w3, h3);
            }
            eA0 = eC0; eA1 = eC1; eA2 = eC2; eA3 = eC3;
            eB0 = eD0; eB1 = eD1; eB2 = eD2; eB3 = eD3;
            gA0 = gN0; gA1 = gN1; gA2 = gN2; gA3 = gN3;
            j += 8;
        }

        float la = Lsp, lb = Lsp;
        pswap(la, lb);                       // la = L0 all lanes, lb = L1 all lanes
        h_att[(size_t)d * HO + lane]      = A2.x / (la + 1e-9f);
        h_att[(size_t)d * HO + 64 + lane] = A2.y / (lb + 1e-9f);
    }
}

// ---------------- node MLP + residual + next-layer node GEMMs (fused) -------
// Same 64-node/block tiling as k_ngemm. After the residual write, the out tile
// (= feats cols of the NEXT layer's h) is still in registers: convert to bf16
// into the dead Xs stripe (per-wave, no cross-wave hazard), re-stage the LDS
// weight region with pw_n[l_next] behind a barrier, and run the 3 gather GEMMs
// in-place. Eliminates the standalone k_ngemm for layers 1,2 + its feats read.
__global__ void __launch_bounds__(256) k_mlp(
        const float* __restrict__ h_att,
        const unsigned short* __restrict__ pw_m0, const void* __restrict__ bm0,
        const unsigned short* __restrict__ pw_m1, const void* __restrict__ bm1, int l,
        float* __restrict__ feats, int prev_off, int out_off,
        const int* __restrict__ flagp,
        const unsigned short* __restrict__ pw_n, int l_next,
        unsigned* __restrict__ gsrc, unsigned* __restrict__ gdst, int do_ng) {
    const int f32 = *flagp;
    // manual LDS carve: Xs 64x136 (17408B) | WB 55296B | sb0 512B | sb1 256B
    // WB holds W0T(128x136=34816) + W1T(64x136=17408) during the MLP, then is
    // re-staged as WsN(384x72=55296) for the ngemm phase.
    __shared__ __align__(16) char SM[73472];
    unsigned short* Xs  = (unsigned short*)SM;
    unsigned short* W0T = (unsigned short*)(SM + 17408);
    unsigned short* W1T = (unsigned short*)(SM + 52224);
    unsigned short* WsN = (unsigned short*)(SM + 17408);
    float* sb0 = (float*)(SM + 72704);
    float* sb1 = (float*)(SM + 73216);
    int tid = threadIdx.x, n0 = blockIdx.x * 64;
    for (int i = tid; i < 64 * 128; i += 256) {
        int n = i >> 7, c = i & 127, gn = n0 + n;
        Xs[n * 136 + c] = rnebf((gn < N_NODES) ? h_att[(size_t)gn * HO + c] : 0.f);
    }
    const uint4* p0 = (const uint4*)pw_m0 + (size_t)l * 2048;
    for (int i = tid; i < 2048; i += 256) {   // i = c*16 + kq
        int kq = i & 15, c = i >> 4;
        *(uint4*)&W0T[c * 136 + kq * 8] = p0[i];
    }
    const uint4* p1 = (const uint4*)pw_m1 + (size_t)l * 1024;
    for (int i = tid; i < 1024; i += 256) {
        int kq = i & 15, c = i >> 4;
        *(uint4*)&W1T[c * 136 + kq * 8] = p1[i];
    }
    for (int i = tid; i < HO; i += 256) sb0[i] = LD(bm0, l * HO + i, f32);
    for (int i = tid; i < 64; i += 256) sb1[i] = LD(bm1, l * 64 + i, f32);
    __syncthreads();
    int wid = tid >> 6, lane = tid & 63;
    int row0 = wid * 16, mrow = lane & 15, quad = lane >> 4;
    f32x4 acc[8];
    #pragma unroll
    for (int j = 0; j < 8; j++) {
        float b = sb0[j * 16 + mrow];
        acc[j] = (f32x4){b, b, b, b};
    }
    #pragma unroll
    for (int ks = 0; ks < 4; ks++) {
        bf16x8 a = *(const bf16x8*)&Xs[(row0 + mrow) * 136 + ks * 32 + quad * 8];
        #pragma unroll
        for (int j = 0; j < 8; j++) {
            bf16x8 b = *(const bf16x8*)&W0T[(j * 16 + mrow) * 136 + ks * 32 + quad * 8];
            acc[j] = __builtin_amdgcn_mfma_f32_16x16x32_bf16(a, b, acc[j], 0, 0, 0);
        }
    }
    // relu -> own stripe of Xs (each wave reads/writes only rows row0..row0+15)
    #pragma unroll
    for (int j = 0; j < 8; j++)
        #pragma unroll
        for (int r = 0; r < 4; r++)
            Xs[(row0 + quad * 4 + r) * 136 + j * 16 + mrow] = rnebf(fmaxf(acc[j][r], 0.f));
    f32x4 o[4];
    #pragma unroll
    for (int j = 0; j < 4; j++) {
        float b = sb1[j * 16 + mrow];
        o[j] = (f32x4){b, b, b, b};
    }
    #pragma unroll
    for (int ks = 0; ks < 4; ks++) {
        bf16x8 a = *(const bf16x8*)&Xs[(row0 + mrow) * 136 + ks * 32 + quad * 8];
        #pragma unroll
        for (int j = 0; j < 4; j++) {
            bf16x8 b = *(const bf16x8*)&W1T[(j * 16 + mrow) * 136 + ks * 32 + quad * 8];
            o[j] = __builtin_amdgcn_mfma_f32_16x16x32_bf16(a, b, o[j], 0, 0, 0);
        }
    }
    // residual add + global write; keep out value for the fused ngemm X tile
    #pragma unroll
    for (int j = 0; j < 4; j++) {
        int c = j * 16 + mrow;
        #pragma unroll
        for (int r = 0; r < 4; r++) {
            int gn = n0 + row0 + quad * 4 + r;
            float outv = 0.f;
            if (gn < N_NODES) {
                float* rw = feats + (size_t)gn * F_TOT;
                outv = o[j][r] + rw[prev_off + c];
                rw[out_off + c] = outv;
            }
            o[j][r] = outv;                  // masked rows become 0 (zero-pad)
        }
    }
    if (do_ng) {
        // X2 (bf16 of out) -> Xs cols 0..63, own stripe (no cross-wave hazard)
        #pragma unroll
        for (int j = 0; j < 4; j++)
            #pragma unroll
            for (int r = 0; r < 4; r++)
                Xs[(row0 + quad * 4 + r) * 136 + j * 16 + mrow] = rnebf(o[j][r]);
        __syncthreads();                     // all waves done with W1T reads
        const uint4* pn = (const uint4*)pw_n + (size_t)l_next * 3072;
        for (int i = tid; i < 3072; i += 256) {   // i = (m*128+c)*8 + kq
            int kq = i & 7, mc = i >> 3;
            *(uint4*)&WsN[mc * 72 + kq * 8] = pn[i];
        }
        __syncthreads();
        bf16x8 a0 = *(const bf16x8*)&Xs[(row0 + mrow) * 136 + quad * 8];
        bf16x8 a1 = *(const bf16x8*)&Xs[(row0 + mrow) * 136 + 32 + quad * 8];
        f32x4 accA[8], accB[8];
        #pragma unroll
        for (int j = 0; j < 8; j++) { accA[j] = (f32x4){0,0,0,0}; accB[j] = (f32x4){0,0,0,0}; }
        #pragma unroll
        for (int j = 0; j < 8; j++) {
            bf16x8 b0 = *(const bf16x8*)&WsN[(0 * 128 + j * 16 + mrow) * 72 + quad * 8];
            bf16x8 b1 = *(const bf16x8*)&WsN[(0 * 128 + j * 16 + mrow) * 72 + 32 + quad * 8];
            accA[j] = __builtin_amdgcn_mfma_f32_16x16x32_bf16(a0, b0, accA[j], 0, 0, 0);
            accA[j] = __builtin_amdgcn_mfma_f32_16x16x32_bf16(a1, b1, accA[j], 0, 0, 0);
            bf16x8 c0 = *(const bf16x8*)&WsN[(2 * 128 + j * 16 + mrow) * 72 + quad * 8];
            bf16x8 c1 = *(const bf16x8*)&WsN[(2 * 128 + j * 16 + mrow) * 72 + 32 + quad * 8];
            accB[j] = __builtin_amdgcn_mfma_f32_16x16x32_bf16(a0, c0, accB[j], 0, 0, 0);
            accB[j] = __builtin_amdgcn_mfma_f32_16x16x32_bf16(a1, c1, accB[j], 0, 0, 0);
        }
        #pragma unroll
        for (int j = 0; j < 4; j++) {
            int c = j * 16 + mrow;
            #pragma unroll
            for (int r = 0; r < 4; r++) {
                int gn = n0 + row0 + quad * 4 + r;
                if (gn < N_NODES) {
                    uint2 v;
                    v.x = pk2(accA[j][r], accA[j + 4][r]);
                    v.y = pk2(accB[j][r], accB[j + 4][r]);
                    *(uint2*)&gsrc[(size_t)gn * 128 + c * 2] = v;
                }
            }
        }
        f32x4 accC[8];
        #pragma unroll
        for (int j = 0; j < 8; j++) accC[j] = (f32x4){0,0,0,0};
        #pragma unroll
        for (int j = 0; j < 8; j++) {
            bf16x8 b0 = *(const bf16x8*)&WsN[(1 * 128 + j * 16 + mrow) * 72 + quad * 8];
            bf16x8 b1 = *(const bf16x8*)&WsN[(1 * 128 + j * 16 + mrow) * 72 + 32 + quad * 8];
            accC[j] = __builtin_amdgcn_mfma_f32_16x16x32_bf16(a0, b0, accC[j], 0, 0, 0);
            accC[j] = __builtin_amdgcn_mfma_f32_16x16x32_bf16(a1, b1, accC[j], 0, 0, 0);
        }
        #pragma unroll
        for (int j = 0; j < 4; j++) {
            int c = j * 16 + mrow;
            #pragma unroll
            for (int r = 0; r < 4; r++) {
                int gn = n0 + row0 + quad * 4 + r;
                if (gn < N_NODES)
                    gdst[(size_t)gn * 64 + c] = pk2(accC[j][r], accC[j + 4][r]);
            }
        }
    }
}

// ---------------- graph max pool -------------------------------------------
__global__ void k_pool(const float* __restrict__ feats, unsigned* __restrict__ gmax) {
    int g = blockIdx.x;
    int chunk = blockIdx.y;
    int t = threadIdx.x;
    const int CS = 49;
    int nb = chunk * CS;
    int ne = (nb + CS < NPG) ? nb + CS : NPG;
    float m0 = -INFINITY, m1 = -INFINITY;
    for (int n = nb; n < ne; n++) {
        const float* row = feats + (size_t)(g * NPG + n) * F_TOT;
        m0 = fmaxf(m0, row[t]);
        if (t + 256 < F_TOT) m1 = fmaxf(m1, row[t + 256]);
    }
    atomicMax(&gmax[g * F_TOT + t], fkey(m0));
    if (t + 256 < F_TOT) atomicMax(&gmax[g * F_TOT + t + 256], fkey(m1));
}

// ---------------- output write: wave per row --------------------------------
__global__ void k_out(const float* __restrict__ feats, const unsigned* __restrict__ gmax,
                      void* __restrict__ out, const int* __restrict__ flagp) {
    const int f32 = *flagp;
    int lane = threadIdx.x & 63;
    int wave = (blockIdx.x * blockDim.x + threadIdx.x) >> 6;
    int nw = (gridDim.x * blockDim.x) >> 6;
    for (int row = wave; row < B_GRAPHS * NPG; row += nw) {
        int g = row / NPG;
        const float* fr = feats + (size_t)row * F_TOT;
        const unsigned* gr = gmax + g * F_TOT;
        if (f32) {
            float* o = (float*)out + (size_t)row * OUT_C;
            for (int c = lane; c < OUT_C; c += 64)
                o[c] = (c < F_TOT) ? fr[c] : funkey(gr[c - F_TOT]);
        } else {
            __hip_bfloat16* o = (__hip_bfloat16*)out + (size_t)row * OUT_C;
            for (int c = lane; c < OUT_C; c += 64)
                o[c] = __float2bfloat16((c < F_TOT) ? fr[c] : funkey(gr[c - F_TOT]));
        }
    }
}

extern "C" void kernel_launch(void* const* d_in, const int* in_sizes, int n_in,
                              void* d_out, int out_size, void* d_ws, size_t ws_size,
                              hipStream_t stream) {
    const void* feat      = d_in[0];
    const void* att_rc    = d_in[1];
    const void* att_rp    = d_in[2];
    const void* etype_emb = d_in[3];
    const void* rid_emb   = d_in[4];
    const void* rc_W      = d_in[5];
    const void* rc_b      = d_in[6];
    const void* rp_W      = d_in[7];
    const void* rp_b      = d_in[8];
    const void* fe_W0     = d_in[9];
    const void* fe_b0     = d_in[10];
    const void* fe_W1     = d_in[11];
    const void* fe_b1     = d_in[12];
    const void* W_ni      = d_in[13];
    const void* W_nj      = d_in[14];
    const void* W_fij     = d_in[15];
    const void* W_node    = d_in[16];
    const void* attn      = d_in[17];
    const void* egat_bias = d_in[18];
    const void* Wm0       = d_in[19];
    const void* bm0       = d_in[20];
    const void* Wm1       = d_in[21];
    const void* bm1       = d_in[22];
    const int* src   = (const int*)d_in[23];
    const int* dst   = (const int*)d_in[24];
    const int* etype = (const int*)d_in[25];
    const int* rid   = (const int*)d_in[26];

    char* p = (char*)d_ws;
    auto alloc = [&](size_t bytes) {
        char* r = p;
        p += (bytes + 255) & ~(size_t)255;
        return r;
    };
    float*    feats  = (float*)alloc((size_t)N_NODES * F_TOT * 4);
    unsigned* gsrc   = (unsigned*)alloc((size_t)N_NODES * HO * 4);
    unsigned* gdst   = (unsigned*)alloc((size_t)N_NODES * 64 * 4);
    float*    h_att  = (float*)alloc((size_t)N_NODES * HO * 4);
    float*    T      = (float*)alloc((size_t)3 * NT_ROWS * HO * 4);
    unsigned* gmax   = (unsigned*)alloc((size_t)B_GRAPHS * F_TOT * 4);
    int*      flagp  = (int*)alloc(256);
    int*      rowptr = (int*)alloc((size_t)(N_NODES + 1) * 4);
    int*      cursor = (int*)alloc((size_t)N_NODES * 4);
    int*      cnt    = (int*)alloc((size_t)N_NODES * 4);
    int*      bsum   = (int*)alloc((size_t)SCB * 4);
    uint4*    emeta  = (uint4*)alloc((size_t)N_EDGES * 16);
    unsigned short* pw_n  = (unsigned short*)alloc((size_t)73728 * 2);
    unsigned short* pw_m0 = (unsigned short*)alloc((size_t)49152 * 2);
    unsigned short* pw_m1 = (unsigned short*)alloc((size_t)24576 * 2);

    k_detect<<<1, 256, 0, stream>>>(att_rc, flagp);
    k_wprep<<<783, 256, 0, stream>>>(W_ni, W_nj, W_node, Wm0, Wm1,
                                     pw_n, pw_m0, pw_m1, flagp,
                                     etype_emb, rid_emb, rc_W, rc_b, rp_W, rp_b,
                                     W_fij, egat_bias, T, cnt, gmax);
    k_count<<<512, 256, 0, stream>>>(dst, cnt);
    k_scan1<<<SCB, 256, 0, stream>>>(cnt, bsum);
    k_scan3<<<SCB, 256, 0, stream>>>(cnt, bsum, rowptr, cursor);
    k_fill<<<1024, 256, 0, stream>>>(src, dst, etype, rid, att_rc, att_rp,
                                     cursor, emeta, flagp);
    k_init<<<(N_NODES + 63) / 64, 256, 0, stream>>>(feat, fe_W0, fe_b0, fe_W1, fe_b1,
                                                    feats, flagp);
    k_ngemm<<<(N_NODES + 63) / 64, 256, 0, stream>>>(feats, IN_DIM, pw_n, 0, gsrc, gdst);
    for (int l = 0; l < 3; l++) {
        int h_off = IN_DIM + l * HID;
        int out_off = IN_DIM + (l + 1) * HID;
        k_edge_fused<<<N_NODES / 8, 256, 0, stream>>>(T, attn, l, gsrc, gdst,
                                                      rowptr, emeta, h_att, flagp);
        k_mlp<<<(N_NODES + 63) / 64, 256, 0, stream>>>(h_att, pw_m0, bm0, pw_m1, bm1, l,
                                                       feats, h_off, out_off, flagp,
                                                       pw_n, l + 1, gsrc, gdst,
                                                       (l < 2) ? 1 : 0);
    }
    k_pool<<<dim3(B_GRAPHS, 128), 256, 0, stream>>>(feats, gmax);
    k_out<<<2048, 256, 0, stream>>>(feats, gmax, d_out, flagp);
}